// Round 1
// baseline (1029.070 us; speedup 1.0000x reference)
//
#include <hip/hip_runtime.h>

typedef _Float16 f16;
typedef _Float16 f16x8 __attribute__((ext_vector_type(8)));
typedef _Float16 f16x4v __attribute__((ext_vector_type(4)));
typedef float f32x4 __attribute__((ext_vector_type(4)));

#define MFMA16(a, b, c) __builtin_amdgcn_mfma_f32_16x16x32_f16(a, b, c, 0, 0, 0)

// =====================================================================
// k_mt: MT[h][f][e] = sum_d Wq[h*H+d][e] * Wk[h*H+d][f]   (f16 output)
// grid: (16 heads, (H/64)^2 tiles), block 256 (4 waves), 64x64 tile
// =====================================================================
__global__ __launch_bounds__(256) void k_mt(const float* __restrict__ Wq,
                                            const float* __restrict__ Wk,
                                            f16* __restrict__ MT, int H) {
    const int h = blockIdx.x;
    const int ntile = H >> 6;
    const int frow = (blockIdx.y / ntile) * 64;
    const int ecol = (blockIdx.y % ntile) * 64;
    const int t = threadIdx.x;
    const int lane = t & 63;
    const int w = t >> 6;
    const int wr = w >> 1, wc = w & 1;

    __shared__ __align__(16) f16 As[64][40]; // [e_local][d] (transposed Wq)
    __shared__ __align__(16) f16 Ks[64][40]; // [f_local][d] (transposed Wk)

    f32x4 acc[2][2] = {};
    const int d = t >> 3;         // 0..31
    const int e8 = (t & 7) * 8;   // 0..56

    const int nk = H >> 5;
    for (int kk = 0; kk < nk; ++kk) {
        const float* gq = Wq + (size_t)(h * H + kk * 32 + d) * H + ecol + e8;
        const float* gk = Wk + (size_t)(h * H + kk * 32 + d) * H + frow + e8;
        float q[8], k[8];
#pragma unroll
        for (int i = 0; i < 8; ++i) { q[i] = gq[i]; k[i] = gk[i]; }
        __syncthreads();
#pragma unroll
        for (int i = 0; i < 8; ++i) { As[e8 + i][d] = (f16)q[i]; Ks[e8 + i][d] = (f16)k[i]; }
        __syncthreads();
        f16x8 a[2], b[2];
#pragma unroll
        for (int rt = 0; rt < 2; ++rt)
            a[rt] = *(const f16x8*)&Ks[wr * 32 + rt * 16 + (lane & 15)][(lane >> 4) * 8];
#pragma unroll
        for (int nt = 0; nt < 2; ++nt)
            b[nt] = *(const f16x8*)&As[wc * 32 + nt * 16 + (lane & 15)][(lane >> 4) * 8];
#pragma unroll
        for (int rt = 0; rt < 2; ++rt)
#pragma unroll
            for (int nt = 0; nt < 2; ++nt)
                acc[rt][nt] = MFMA16(a[rt], b[nt], acc[rt][nt]);
    }
#pragma unroll
    for (int rt = 0; rt < 2; ++rt)
#pragma unroll
        for (int nt = 0; nt < 2; ++nt)
#pragma unroll
            for (int j = 0; j < 4; ++j) {
                int f = frow + wr * 32 + rt * 16 + (lane >> 4) * 4 + j;
                int e = ecol + wc * 32 + nt * 16 + (lane & 15);
                MT[(size_t)(h * H + f) * H + e] = (f16)acc[rt][nt][j];
            }
}

// =====================================================================
// f32 -> f16 flat convert
// =====================================================================
__global__ void k_f32_to_f16(const float* __restrict__ in, f16* __restrict__ out, int n) {
    int i = (blockIdx.x * blockDim.x + threadIdx.x) * 4;
    int stride = gridDim.x * blockDim.x * 4;
    for (; i < n; i += stride) {
        float4 v = *(const float4*)(in + i);
        f16x4v o;
        o[0] = (f16)v.x; o[1] = (f16)v.y; o[2] = (f16)v.z; o[3] = (f16)v.w;
        *(f16x4v*)(out + i) = o;
    }
}

// =====================================================================
// k_lin: out[r][j] = sum_d in[r][d]*W[j][d] + b[j], J=256 fixed, 8 rows/block
// =====================================================================
__global__ __launch_bounds__(256) void k_lin(const float* __restrict__ in,
                                             const float* __restrict__ W,
                                             const float* __restrict__ bias,
                                             float* __restrict__ out, int K) {
    const int t = threadIdx.x;
    const int r0 = blockIdx.x * 8;
    __shared__ float ins[8][384];
    __shared__ float Ws[256][33];
#pragma unroll
    for (int r = 0; r < 8; ++r)
        for (int off = t; off < K; off += 256)
            ins[r][off] = in[(size_t)(r0 + r) * K + off];
    float acc[8] = {};
    for (int d0 = 0; d0 < K; d0 += 32) {
        __syncthreads();
        for (int i = t; i < 256 * 32; i += 256) {
            int j = i >> 5, dd = i & 31;
            Ws[j][dd] = W[(size_t)j * K + d0 + dd];
        }
        __syncthreads();
#pragma unroll 8
        for (int dd = 0; dd < 32; ++dd) {
            float wv = Ws[t][dd];
#pragma unroll
            for (int r = 0; r < 8; ++r) acc[r] += wv * ins[r][d0 + dd];
        }
    }
    float bv = bias[t];
#pragma unroll
    for (int r = 0; r < 8; ++r) out[(size_t)(r0 + r) * 256 + t] = acc[r] + bv;
}

// =====================================================================
// k_small_int: fused integrate for Ls=4 (states), hidden=256, rank=16.
// X layout: [4 states][256 pos][256].  4 positions/block, loop 16 heads.
// grid 64, block 256 (4 waves).
// =====================================================================
__global__ __launch_bounds__(256) void k_small_int(const float* __restrict__ X,
                                                   const f16* __restrict__ MT,
                                                   float* __restrict__ out_int,
                                                   float* __restrict__ out_w) {
    const int t = threadIdx.x;
    const int lane = t & 63;
    const int w = t >> 6;
    const int pos0 = blockIdx.x * 4;

    __shared__ __align__(16) f16 Xs[16][264];  // rows: p*4+s
    __shared__ __align__(16) f16 Ms[256][40];  // MT[h][f][e-chunk]
    __shared__ __align__(16) f16 Ts[16][264];  // T = X*M
    __shared__ float accb[4][4];
    __shared__ float wbuf[4][4];

    {
        int row = t >> 4, d0 = (t & 15) * 16;
        int s = row & 3, p = row >> 2;
        const float* g = X + (size_t)(s * 256 + pos0 + p) * 256 + d0;
#pragma unroll
        for (int i = 0; i < 16; ++i) Xs[row][d0 + i] = (f16)g[i];
    }
    if (t < 16) accb[t >> 2][t & 3] = 0.f;
    __syncthreads();

    const float scale = 1.0f / 16.0f; // 1/sqrt(256)

    for (int h = 0; h < 16; ++h) {
        f32x4 acc[4] = {}; // T cols: w*64 + nt*16
        for (int kk = 0; kk < 8; ++kk) {
            const f16* g = MT + ((size_t)(h * 256 + t) * 256 + kk * 32);
            int4 r0 = *(const int4*)(g);
            int4 r1 = *(const int4*)(g + 8);
            int4 r2 = *(const int4*)(g + 16);
            int4 r3 = *(const int4*)(g + 24);
            __syncthreads();
            *(int4*)&Ms[t][0] = r0;  *(int4*)&Ms[t][8] = r1;
            *(int4*)&Ms[t][16] = r2; *(int4*)&Ms[t][24] = r3;
            __syncthreads();
            f16x8 a = *(const f16x8*)&Xs[lane & 15][kk * 32 + (lane >> 4) * 8];
#pragma unroll
            for (int nt = 0; nt < 4; ++nt) {
                f16x8 b = *(const f16x8*)&Ms[w * 64 + nt * 16 + (lane & 15)][(lane >> 4) * 8];
                acc[nt] = MFMA16(a, b, acc[nt]);
            }
        }
        __syncthreads();
#pragma unroll
        for (int nt = 0; nt < 4; ++nt)
#pragma unroll
            for (int j = 0; j < 4; ++j)
                Ts[(lane >> 4) * 4 + j][w * 64 + nt * 16 + (lane & 15)] = (f16)acc[nt][j];
        __syncthreads();
        if (w == 0) {
            f32x4 sacc = {};
#pragma unroll
            for (int ks = 0; ks < 8; ++ks) {
                f16x8 a = *(const f16x8*)&Ts[lane & 15][ks * 32 + (lane >> 4) * 8];
                f16x8 b = *(const f16x8*)&Xs[lane & 15][ks * 32 + (lane >> 4) * 8];
                sacc = MFMA16(a, b, sacc);
            }
            // diag 4x4 blocks: active lanes l = p*20 + ms
            bool active = ((lane & 15) >> 2) == (lane >> 4);
            if (active) {
                float add = 0.f;
#pragma unroll
                for (int j = 0; j < 4; ++j) {
                    float v = sacc[j] * scale;
                    float m = v;
                    m = fmaxf(m, __shfl_xor(m, 1));
                    m = fmaxf(m, __shfl_xor(m, 2));
                    float e = expf(v - m);
                    float s = e;
                    s += __shfl_xor(s, 1);
                    s += __shfl_xor(s, 2);
                    add += e / s;
                }
                int p = lane >> 4, ms = lane & 3;
                accb[p][ms] += add;
            }
        }
        __syncthreads();
    }

    if (t < 4) {
        float vv[4];
        float m = -1e30f;
#pragma unroll
        for (int s = 0; s < 4; ++s) { vv[s] = accb[t][s] * (1.0f / 64.0f); m = fmaxf(m, vv[s]); }
        float sum = 0.f;
#pragma unroll
        for (int s = 0; s < 4; ++s) { vv[s] = expf(vv[s] - m); sum += vv[s]; }
#pragma unroll
        for (int s = 0; s < 4; ++s) {
            float wv = vv[s] / sum;
            wbuf[t][s] = wv;
            out_w[(pos0 + t) * 4 + s] = wv;
        }
    }
    __syncthreads();
#pragma unroll
    for (int p = 0; p < 4; ++p) {
        float v = 0.f;
#pragma unroll
        for (int s = 0; s < 4; ++s)
            v += wbuf[p][s] * X[(size_t)(s * 256 + pos0 + p) * 256 + t];
        out_int[(size_t)(pos0 + p) * 256 + t] = v;
    }
}

// =====================================================================
// k_ce_int: per-(head, 2-batch) fused  S = (X M_h) X^T -> softmax -> col-sums
// Xg: [32768 tokens][384] f16, MT: [16][384][384] f16, acc_out: [16][1024][32]
// grid (512, 16), block 512 (8 waves). Dynamic LDS = 80896 B.
// =====================================================================
__global__ __launch_bounds__(512, 4) void k_ce_int(const f16* __restrict__ Xg,
                                                   const f16* __restrict__ MT,
                                                   float* __restrict__ acc_out) {
    const int t = threadIdx.x;
    const int lane = t & 63;
    const int w = t >> 6;       // 0..7
    const int wr = w >> 2;      // row half
    const int wc = w & 3;       // col quarter
    const int bg = blockIdx.x;  // 0..511 (2 b's each)
    const int h = blockIdx.y;   // 0..15

    extern __shared__ __align__(16) char smem[];
    f16(*Xs)[392] = (f16(*)[392])smem;                         // 50176 B
    f16(*Ms)[40] = (f16(*)[40])(smem + 50176);                 // 30720 B
    f16(*Ts)[200] = (f16(*)[200])(smem + 50176);               // alias, 25600 B
    float(*accpart)[32] = (float(*)[32])(smem + 50176 + 25600);// 512 B (inside Ms tail)

    // ---- stage X (64 tokens x 384) f16 ----
    {
        const f16* gbase = Xg + (size_t)bg * 64 * 384;
#pragma unroll
        for (int p = 0; p < 6; ++p) {
            int idx = p * 512 + t;      // 16B units, 3072 total
            int row = idx / 48;
            int c8 = (idx % 48) * 8;
            int4 v = *(const int4*)(gbase + (size_t)row * 384 + c8);
            *(int4*)&Xs[row][c8] = v;
        }
    }
    __syncthreads();

    // ---- phase 1: T = X(64x384) @ M_h ; wave: rows wr*32+[0,32), cols wc*96+[0,96)
    f32x4 acc[2][6] = {};
    const f16* mbase = MT + (size_t)h * 384 * 384;
    for (int kk = 0; kk < 12; ++kk) {
        int4 r[3];
#pragma unroll
        for (int p = 0; p < 3; ++p) {
            int idx = p * 512 + t;   // 1536 units: f = idx/4, e8 = (idx&3)*8
            int f = idx >> 2;
            int e8 = (idx & 3) * 8;
            r[p] = *(const int4*)(mbase + (size_t)f * 384 + kk * 32 + e8);
        }
        __syncthreads();
#pragma unroll
        for (int p = 0; p < 3; ++p) {
            int idx = p * 512 + t;
            int f = idx >> 2;
            int e8 = (idx & 3) * 8;
            *(int4*)&Ms[f][e8] = r[p];
        }
        __syncthreads();
        f16x8 a[2];
#pragma unroll
        for (int rt = 0; rt < 2; ++rt)
            a[rt] = *(const f16x8*)&Xs[wr * 32 + rt * 16 + (lane & 15)][kk * 32 + (lane >> 4) * 8];
#pragma unroll
        for (int nt = 0; nt < 6; ++nt) {
            f16x8 b = *(const f16x8*)&Ms[wc * 96 + nt * 16 + (lane & 15)][(lane >> 4) * 8];
            acc[0][nt] = MFMA16(a[0], b, acc[0][nt]);
            acc[1][nt] = MFMA16(a[1], b, acc[1][nt]);
        }
    }
    __syncthreads();

    // ---- phase 2: S_b = T_b @ X_b^T, f-chunked (2 x 192) ----
    const int b = w >> 1;   // for waves 0..3
    const int lh = w & 1;
    f32x4 sacc[2] = {};
#pragma unroll
    for (int c = 0; c < 2; ++c) {
        if ((wc >> 1) == c) {
#pragma unroll
            for (int rt = 0; rt < 2; ++rt)
#pragma unroll
                for (int nt = 0; nt < 6; ++nt)
#pragma unroll
                    for (int j = 0; j < 4; ++j)
                        Ts[wr * 32 + rt * 16 + (lane >> 4) * 4 + j]
                          [(wc & 1) * 96 + nt * 16 + (lane & 15)] = (f16)acc[rt][nt][j];
        }
        __syncthreads();
        if (w < 4) {
#pragma unroll
            for (int ks = 0; ks < 6; ++ks) {
                f16x8 a = *(const f16x8*)&Ts[b * 32 + lh * 16 + (lane & 15)][ks * 32 + (lane >> 4) * 8];
#pragma unroll
                for (int nt = 0; nt < 2; ++nt) {
                    f16x8 bb = *(const f16x8*)&Xs[b * 32 + nt * 16 + (lane & 15)]
                                                 [c * 192 + ks * 32 + (lane >> 4) * 8];
                    sacc[nt] = MFMA16(a, bb, sacc[nt]);
                }
            }
        }
        __syncthreads();
    }

    // ---- softmax rows + column sums (waves 0..3) ----
    if (w < 4) {
        const float scale = 0.051031036307982884f; // 1/sqrt(384)
        float cp0 = 0.f, cp1 = 0.f;
#pragma unroll
        for (int j = 0; j < 4; ++j) {
            float v0 = sacc[0][j] * scale, v1 = sacc[1][j] * scale;
            float m = fmaxf(v0, v1);
            m = fmaxf(m, __shfl_xor(m, 1));
            m = fmaxf(m, __shfl_xor(m, 2));
            m = fmaxf(m, __shfl_xor(m, 4));
            m = fmaxf(m, __shfl_xor(m, 8));
            float e0 = expf(v0 - m), e1 = expf(v1 - m);
            float s = e0 + e1;
            s += __shfl_xor(s, 1);
            s += __shfl_xor(s, 2);
            s += __shfl_xor(s, 4);
            s += __shfl_xor(s, 8);
            float inv = 1.f / s;
            cp0 += e0 * inv; cp1 += e1 * inv;
        }
        cp0 += __shfl_xor(cp0, 16); cp0 += __shfl_xor(cp0, 32);
        cp1 += __shfl_xor(cp1, 16); cp1 += __shfl_xor(cp1, 32);
        if (lane < 16) {
            accpart[w][lane] = cp0;
            accpart[w][16 + lane] = cp1;
        }
    }
    __syncthreads();
    if (t < 64) {
        int bb = t >> 5, m = t & 31;
        float v = accpart[bb * 2][m] + accpart[bb * 2 + 1][m];
        acc_out[((size_t)h * 1024 + bg * 2 + bb) * 32 + m] = v;
    }
}

// =====================================================================
// k_ce_pool: w = softmax(sum_h accp / 512); pooled[b] = sum_m w[m]*exv[b][m][:]
// =====================================================================
__global__ __launch_bounds__(128) void k_ce_pool(const float* __restrict__ accp,
                                                 const float* __restrict__ exv,
                                                 float* __restrict__ pooled) {
    const int b = blockIdx.x;
    const int t = threadIdx.x;
    __shared__ float wm[32];
    __shared__ float ww[32];
    if (t < 32) {
        float s = 0.f;
#pragma unroll
        for (int h = 0; h < 16; ++h) s += accp[((size_t)h * 1024 + b) * 32 + t];
        wm[t] = s * (1.0f / 512.0f);
    }
    __syncthreads();
    if (t == 0) {
        float m = wm[0];
        for (int i = 1; i < 32; ++i) m = fmaxf(m, wm[i]);
        float s = 0.f;
        for (int i = 0; i < 32; ++i) { float e = expf(wm[i] - m); ww[i] = e; s += e; }
        float inv = 1.f / s;
        for (int i = 0; i < 32; ++i) ww[i] *= inv;
    }
    __syncthreads();
    for (int d = t; d < 384; d += 128) {
        float v = 0.f;
#pragma unroll
        for (int m = 0; m < 32; ++m) v += ww[m] * exv[((size_t)b * 32 + m) * 384 + d];
        pooled[(size_t)b * 384 + d] = v;
    }
}

// =====================================================================
extern "C" void kernel_launch(void* const* d_in, const int* in_sizes, int n_in,
                              void* d_out, int out_size, void* d_ws, size_t ws_size,
                              hipStream_t stream) {
    const float* h_V    = (const float*)d_in[0];
    const float* h_EXV  = (const float*)d_in[1];
    const float* W_hV   = (const float*)d_in[2];
    const float* b_hV   = (const float*)d_in[3];
    const float* Wq_hv  = (const float*)d_in[4];
    const float* Wk_hv  = (const float*)d_in[5];
    const float* Wq_ce  = (const float*)d_in[6];
    const float* Wk_ce  = (const float*)d_in[7];
    const float* W_ce   = (const float*)d_in[8];
    const float* b_ce   = (const float*)d_in[9];
    const float* Wq_sce = (const float*)d_in[10];
    const float* Wk_sce = (const float*)d_in[11];
    float* out = (float*)d_out;

    char* ws = (char*)d_ws;
    f16*   mt_hv  = (f16*)(ws + 0);           //  2,097,152
    f16*   mt_sce = (f16*)(ws + 2097152);     //  2,097,152
    f16*   mt_ce  = (f16*)(ws + 4194304);     //  4,718,592
    f16*   exv16  = (f16*)(ws + 8912896);     // 25,165,824
    float* hv     = (float*)(ws + 34078720);  //  1,048,576
    float* ce     = (float*)(ws + 35127296);  //  1,048,576
    float* accp   = (float*)(ws + 36175872);  //  2,097,152
    float* pooled = (float*)(ws + 38273024);  //  1,572,864  (total ~38 MB)

    k_mt<<<dim3(16, 16), 256, 0, stream>>>(Wq_hv, Wk_hv, mt_hv, 256);
    k_mt<<<dim3(16, 36), 256, 0, stream>>>(Wq_ce, Wk_ce, mt_ce, 384);
    k_mt<<<dim3(16, 16), 256, 0, stream>>>(Wq_sce, Wk_sce, mt_sce, 256);
    k_f32_to_f16<<<2048, 256, 0, stream>>>(h_EXV, exv16, 12582912);
    k_lin<<<128, 256, 0, stream>>>(h_V, W_hV, b_hV, hv, 128);
    k_small_int<<<64, 256, 0, stream>>>(hv, mt_hv, out + 0, out + 65536);
    k_ce_int<<<dim3(512, 16), 512, 80896, stream>>>(exv16, mt_ce, accp);
    k_ce_pool<<<1024, 128, 0, stream>>>(accp, h_EXV, pooled);
    k_lin<<<128, 256, 0, stream>>>(pooled, W_ce, b_ce, ce, 384);
    k_small_int<<<64, 256, 0, stream>>>(ce, mt_sce, out + 66560, out + 132096);
}

// Round 2
// 407.407 us; speedup vs baseline: 2.5259x; 2.5259x over previous
//
#include <hip/hip_runtime.h>

typedef _Float16 f16;
typedef _Float16 f16x8 __attribute__((ext_vector_type(8)));
typedef _Float16 f16x4v __attribute__((ext_vector_type(4)));
typedef float f32x4 __attribute__((ext_vector_type(4)));

#define MFMA16(a, b, c) __builtin_amdgcn_mfma_f32_16x16x32_f16(a, b, c, 0, 0, 0)

// =====================================================================
// k_mt: M_h = Wq_h^T Wk_h, stored K-blocked+transposed:
//   MT[((h*nkk + (e>>5))*H + f)*32 + (e&31)] = sum_d Wq[h*H+d][e]*Wk[h*H+d][f]
// grid (16 heads, (H/64)^2), block 256.
// =====================================================================
__global__ __launch_bounds__(256) void k_mt(const float* __restrict__ Wq,
                                            const float* __restrict__ Wk,
                                            f16* __restrict__ MT, int H) {
    const int h = blockIdx.x;
    const int ntile = H >> 6;
    const int nkk = H >> 5;
    const int frow = (blockIdx.y / ntile) * 64;
    const int ecol = (blockIdx.y % ntile) * 64;
    const int t = threadIdx.x;
    const int lane = t & 63;
    const int w = t >> 6;
    const int wr = w >> 1, wc = w & 1;

    __shared__ __align__(16) f16 As[64][40];
    __shared__ __align__(16) f16 Ks[64][40];

    f32x4 acc[2][2] = {};
    const int d = t >> 3;
    const int e8 = (t & 7) * 8;

    for (int kk = 0; kk < nkk; ++kk) {
        const float* gq = Wq + (size_t)(h * H + kk * 32 + d) * H + ecol + e8;
        const float* gk = Wk + (size_t)(h * H + kk * 32 + d) * H + frow + e8;
        float q[8], k[8];
#pragma unroll
        for (int i = 0; i < 8; ++i) { q[i] = gq[i]; k[i] = gk[i]; }
        __syncthreads();
#pragma unroll
        for (int i = 0; i < 8; ++i) { As[e8 + i][d] = (f16)q[i]; Ks[e8 + i][d] = (f16)k[i]; }
        __syncthreads();
        f16x8 a[2], b[2];
#pragma unroll
        for (int rt = 0; rt < 2; ++rt)
            a[rt] = *(const f16x8*)&Ks[wr * 32 + rt * 16 + (lane & 15)][(lane >> 4) * 8];
#pragma unroll
        for (int nt = 0; nt < 2; ++nt)
            b[nt] = *(const f16x8*)&As[wc * 32 + nt * 16 + (lane & 15)][(lane >> 4) * 8];
#pragma unroll
        for (int rt = 0; rt < 2; ++rt)
#pragma unroll
            for (int nt = 0; nt < 2; ++nt)
                acc[rt][nt] = MFMA16(a[rt], b[nt], acc[rt][nt]);
    }
#pragma unroll
    for (int rt = 0; rt < 2; ++rt)
#pragma unroll
        for (int nt = 0; nt < 2; ++nt)
#pragma unroll
            for (int j = 0; j < 4; ++j) {
                int f = frow + wr * 32 + rt * 16 + (lane >> 4) * 4 + j;
                int e = ecol + wc * 32 + nt * 16 + (lane & 15);
                MT[(((size_t)h * nkk + (e >> 5)) * H + f) * 32 + (e & 31)] = (f16)acc[rt][nt][j];
            }
}

// =====================================================================
__global__ void k_f32_to_f16(const float* __restrict__ in, f16* __restrict__ out, int n) {
    int i = (blockIdx.x * blockDim.x + threadIdx.x) * 4;
    int stride = gridDim.x * blockDim.x * 4;
    for (; i < n; i += stride) {
        float4 v = *(const float4*)(in + i);
        f16x4v o;
        o[0] = (f16)v.x; o[1] = (f16)v.y; o[2] = (f16)v.z; o[3] = (f16)v.w;
        *(f16x4v*)(out + i) = o;
    }
}

// =====================================================================
// k_lin: out[r][j] = sum_d in[r][d]*W[j][d] + b[j], J=256 fixed, 8 rows/block
// =====================================================================
__global__ __launch_bounds__(256) void k_lin(const float* __restrict__ in,
                                             const float* __restrict__ W,
                                             const float* __restrict__ bias,
                                             float* __restrict__ out, int K) {
    const int t = threadIdx.x;
    const int r0 = blockIdx.x * 8;
    __shared__ float ins[8][384];
    __shared__ float Ws[256][33];
#pragma unroll
    for (int r = 0; r < 8; ++r)
        for (int off = t; off < K; off += 256)
            ins[r][off] = in[(size_t)(r0 + r) * K + off];
    float acc[8] = {};
    for (int d0 = 0; d0 < K; d0 += 32) {
        __syncthreads();
        for (int i = t; i < 256 * 32; i += 256) {
            int j = i >> 5, dd = i & 31;
            Ws[j][dd] = W[(size_t)j * K + d0 + dd];
        }
        __syncthreads();
#pragma unroll 8
        for (int dd = 0; dd < 32; ++dd) {
            float wv = Ws[t][dd];
#pragma unroll
            for (int r = 0; r < 8; ++r) acc[r] += wv * ins[r][d0 + dd];
        }
    }
    float bv = bias[t];
#pragma unroll
    for (int r = 0; r < 8; ++r) out[(size_t)(r0 + r) * 256 + t] = acc[r] + bv;
}

// =====================================================================
// k_small_int: one (4-pos group, head) per block; partial head-sums to wpart.
// grid (64, 16), block 256.
// =====================================================================
__global__ __launch_bounds__(256) void k_small_int(const float* __restrict__ X,
                                                   const f16* __restrict__ MT,
                                                   float* __restrict__ wpart) {
    const int t = threadIdx.x;
    const int lane = t & 63;
    const int w = t >> 6;
    const int pos0 = blockIdx.x * 4;
    const int h = blockIdx.y;

    __shared__ __align__(16) f16 Xs[16][264];
    __shared__ __align__(16) f16 Ms[256][40];
    __shared__ __align__(16) f16 Ts[16][264];

    {
        int row = t >> 4, d0 = (t & 15) * 16;
        int s = row & 3, p = row >> 2;
        const float* gx = X + (size_t)(s * 256 + pos0 + p) * 256 + d0;
#pragma unroll
        for (int i = 0; i < 16; ++i) Xs[row][d0 + i] = (f16)gx[i];
    }
    __syncthreads();

    f32x4 acc[4] = {};
    for (int kk = 0; kk < 8; ++kk) {
        const f16* gm = MT + ((size_t)(h * 8 + kk) * 256 + t) * 32;
        int4 q0 = *(const int4*)(gm);
        int4 q1 = *(const int4*)(gm + 8);
        int4 q2 = *(const int4*)(gm + 16);
        int4 q3 = *(const int4*)(gm + 24);
        __syncthreads();
        *(int4*)&Ms[t][0] = q0;  *(int4*)&Ms[t][8] = q1;
        *(int4*)&Ms[t][16] = q2; *(int4*)&Ms[t][24] = q3;
        __syncthreads();
        f16x8 a = *(const f16x8*)&Xs[lane & 15][kk * 32 + (lane >> 4) * 8];
#pragma unroll
        for (int nt = 0; nt < 4; ++nt) {
            f16x8 b = *(const f16x8*)&Ms[w * 64 + nt * 16 + (lane & 15)][(lane >> 4) * 8];
            acc[nt] = MFMA16(a, b, acc[nt]);
        }
    }
    __syncthreads();
#pragma unroll
    for (int nt = 0; nt < 4; ++nt)
#pragma unroll
        for (int j = 0; j < 4; ++j)
            Ts[(lane >> 4) * 4 + j][w * 64 + nt * 16 + (lane & 15)] = (f16)acc[nt][j];
    __syncthreads();
    if (w == 0) {
        f32x4 sacc = {};
#pragma unroll
        for (int ks = 0; ks < 8; ++ks) {
            f16x8 a = *(const f16x8*)&Ts[lane & 15][ks * 32 + (lane >> 4) * 8];
            f16x8 b = *(const f16x8*)&Xs[lane & 15][ks * 32 + (lane >> 4) * 8];
            sacc = MFMA16(a, b, sacc);
        }
        bool active = ((lane & 15) >> 2) == (lane >> 4);
        if (active) {
            const float scale = 1.0f / 16.0f; // 1/sqrt(256)
            float add = 0.f;
#pragma unroll
            for (int j = 0; j < 4; ++j) {
                float v = sacc[j] * scale;
                float m = v;
                m = fmaxf(m, __shfl_xor(m, 1));
                m = fmaxf(m, __shfl_xor(m, 2));
                float e = expf(v - m);
                float s2 = e;
                s2 += __shfl_xor(s2, 1);
                s2 += __shfl_xor(s2, 2);
                add += e / s2;
            }
            int p = lane >> 4, ms = lane & 3;
            wpart[((size_t)h * 256 + pos0 + p) * 4 + ms] = add;
        }
    }
}

// =====================================================================
// k_small_fin: sum 16 head-partials -> /64 -> softmax(4) -> pool states.
// grid 256 (one pos each), block 256.
// =====================================================================
__global__ __launch_bounds__(256) void k_small_fin(const float* __restrict__ wpart,
                                                   const float* __restrict__ X,
                                                   float* __restrict__ out_int,
                                                   float* __restrict__ out_w) {
    const int pos = blockIdx.x, t = threadIdx.x;
    __shared__ float red[64];
    __shared__ float ws[4];
    if (t < 64) red[t] = wpart[((size_t)(t >> 2) * 256 + pos) * 4 + (t & 3)];
    __syncthreads();
    if (t == 0) {
        float v[4];
#pragma unroll
        for (int s = 0; s < 4; ++s) {
            float x = 0.f;
            for (int hh = 0; hh < 16; ++hh) x += red[hh * 4 + s];
            v[s] = x * (1.0f / 64.0f);
        }
        float m = fmaxf(fmaxf(v[0], v[1]), fmaxf(v[2], v[3]));
        float sum = 0.f;
#pragma unroll
        for (int s = 0; s < 4; ++s) { v[s] = expf(v[s] - m); sum += v[s]; }
#pragma unroll
        for (int s = 0; s < 4; ++s) ws[s] = v[s] / sum;
    }
    __syncthreads();
    if (t < 4) out_w[pos * 4 + t] = ws[t];
    float v = 0.f;
#pragma unroll
    for (int s = 0; s < 4; ++s) v += ws[s] * X[(size_t)(s * 256 + pos) * 256 + t];
    out_int[(size_t)pos * 256 + t] = v;
}

// =====================================================================
// k_ce_int v2: swizzled LDS, reg-prefetched M chunks, no spill.
// Xg: [32768][384] f16, MT blocked [16][12][384][32] f16, acc_out [16][1024][32]
// grid (512, 16), block 512, dynamic LDS 74240 B.
// =====================================================================
#define X_OFF 0
#define MS_OFF 49152
#define ACC_OFF 73728

__global__ __launch_bounds__(512) void k_ce_int(const f16* __restrict__ Xg,
                                                const f16* __restrict__ MT,
                                                float* __restrict__ acc_out) {
    const int t = threadIdx.x;
    const int lane = t & 63;
    const int w = t >> 6;
    const int wr = w >> 2;
    const int wc = w & 3;
    const int bg = blockIdx.x;
    const int h = blockIdx.y;
    const int g = lane >> 4;

    extern __shared__ __align__(16) char smem[];
    float(*accpart)[32] = (float(*)[32])(smem + ACC_OFF);

    // ---- stage X (64 x 384 f16), source-swizzled, linear LDS ----
    {
        const f16* xg = Xg + (size_t)bg * 64 * 384;
#pragma unroll
        for (int p = 0; p < 6; ++p) {
            int idx = p * 512 + t;
            int row = idx / 48, s = idx - row * 48;
            int c = s ^ (row & 7);
            int4 v = *(const int4*)(xg + row * 384 + c * 8);
            *(int4*)(smem + idx * 16) = v;
        }
    }

    // ---- M chunk reg-prefetch (kk=0) ----
    const f16* mb0 = MT + (size_t)h * 12 * 384 * 32;
    const int fb = t >> 2;                 // f for p=0; +128 per p
    const int mc = (t & 3) ^ (fb & 3);     // swizzled source chunk (same all p)
    int4 r0, r1, r2;
    {
        const f16* mp = mb0 + fb * 32 + mc * 8;
        r0 = *(const int4*)(mp);
        r1 = *(const int4*)(mp + 4096);
        r2 = *(const int4*)(mp + 8192);
    }
    __syncthreads();
    *(int4*)(smem + MS_OFF + t * 16) = r0;
    *(int4*)(smem + MS_OFF + t * 16 + 8192) = r1;
    *(int4*)(smem + MS_OFF + t * 16 + 16384) = r2;
    __syncthreads();

    // ---- phase 1: T = X @ M_h; wave: rows wr*32+[0,32), cols wc*96+[0,96) ----
    f32x4 acc[2][6] = {};
    const int ar0 = wr * 32 + (lane & 15);
    for (int kk = 0; kk < 12; ++kk) {
        if (kk < 11) {  // issue next-chunk loads; drain at post-compute barrier
            const f16* mp = mb0 + (size_t)(kk + 1) * 384 * 32 + fb * 32 + mc * 8;
            r0 = *(const int4*)(mp);
            r1 = *(const int4*)(mp + 4096);
            r2 = *(const int4*)(mp + 8192);
        }
        f16x8 a[2];
#pragma unroll
        for (int rt = 0; rt < 2; ++rt) {
            int row = ar0 + rt * 16;
            int ch = kk * 4 + g;
            a[rt] = *(const f16x8*)(smem + row * 768 + ((ch ^ (row & 7)) << 4));
        }
#pragma unroll
        for (int nt = 0; nt < 6; ++nt) {
            int f = wc * 96 + nt * 16 + (lane & 15);
            f16x8 b = *(const f16x8*)(smem + MS_OFF + f * 64 + ((g ^ (f & 3)) << 4));
            acc[0][nt] = MFMA16(a[0], b, acc[0][nt]);
            acc[1][nt] = MFMA16(a[1], b, acc[1][nt]);
        }
        __syncthreads();
        if (kk < 11) {
            *(int4*)(smem + MS_OFF + t * 16) = r0;
            *(int4*)(smem + MS_OFF + t * 16 + 8192) = r1;
            *(int4*)(smem + MS_OFF + t * 16 + 16384) = r2;
            __syncthreads();
        }
    }

    // ---- phase 2: S_b = T_b @ X_b^T, f-chunked (2 x 192), Ts aliases Ms ----
    const int b = w >> 1;
    const int lh = w & 1;
    f32x4 sacc[2] = {};
#pragma unroll
    for (int cc = 0; cc < 2; ++cc) {
        if ((wc >> 1) == cc) {
#pragma unroll
            for (int rt = 0; rt < 2; ++rt)
#pragma unroll
                for (int nt = 0; nt < 6; ++nt)
#pragma unroll
                    for (int j = 0; j < 4; ++j) {
                        int row = wr * 32 + rt * 16 + (lane >> 4) * 4 + j;
                        int col = (wc & 1) * 96 + nt * 16 + (lane & 15);
                        int ch = col >> 3;
                        *(f16*)(smem + MS_OFF + row * 384 + ((ch ^ (row & 7)) << 4) +
                                (col & 7) * 2) = (f16)acc[rt][nt][j];
                    }
        }
        __syncthreads();
        if (w < 4) {
#pragma unroll
            for (int ks = 0; ks < 6; ++ks) {
                int arr = b * 32 + lh * 16 + (lane & 15);
                int ach = ks * 4 + g;
                f16x8 a = *(const f16x8*)(smem + MS_OFF + arr * 384 + ((ach ^ (arr & 7)) << 4));
#pragma unroll
                for (int nt = 0; nt < 2; ++nt) {
                    int br = b * 32 + nt * 16 + (lane & 15);
                    int bch = cc * 24 + ks * 4 + g;
                    f16x8 bb = *(const f16x8*)(smem + br * 768 + ((bch ^ (br & 7)) << 4));
                    sacc[nt] = MFMA16(a, bb, sacc[nt]);
                }
            }
        }
        __syncthreads();
    }

    // ---- softmax rows + column partial sums ----
    if (w < 4) {
        const float scale = 0.051031036307982884f; // 1/sqrt(384)
        float cp0 = 0.f, cp1 = 0.f;
#pragma unroll
        for (int j = 0; j < 4; ++j) {
            float v0 = sacc[0][j] * scale, v1 = sacc[1][j] * scale;
            float m = fmaxf(v0, v1);
            m = fmaxf(m, __shfl_xor(m, 1));
            m = fmaxf(m, __shfl_xor(m, 2));
            m = fmaxf(m, __shfl_xor(m, 4));
            m = fmaxf(m, __shfl_xor(m, 8));
            float e0 = expf(v0 - m), e1 = expf(v1 - m);
            float s = e0 + e1;
            s += __shfl_xor(s, 1);
            s += __shfl_xor(s, 2);
            s += __shfl_xor(s, 4);
            s += __shfl_xor(s, 8);
            float inv = 1.f / s;
            cp0 += e0 * inv; cp1 += e1 * inv;
        }
        cp0 += __shfl_xor(cp0, 16); cp0 += __shfl_xor(cp0, 32);
        cp1 += __shfl_xor(cp1, 16); cp1 += __shfl_xor(cp1, 32);
        if (lane < 16) {
            accpart[w][lane] = cp0;
            accpart[w][16 + lane] = cp1;
        }
    }
    __syncthreads();
    if (t < 64) {
        int bb = t >> 5, m = t & 31;
        float v = accpart[bb * 2][m] + accpart[bb * 2 + 1][m];
        acc_out[((size_t)h * 1024 + bg * 2 + bb) * 32 + m] = v;
    }
}

// =====================================================================
// k_ce_pool: w = softmax(sum_h accp / 512); pooled[b] = sum_m w[m]*exv[b][m][:]
// =====================================================================
__global__ __launch_bounds__(128) void k_ce_pool(const float* __restrict__ accp,
                                                 const float* __restrict__ exv,
                                                 float* __restrict__ pooled) {
    const int b = blockIdx.x;
    const int t = threadIdx.x;
    __shared__ float wm[32];
    __shared__ float ww[32];
    if (t < 32) {
        float s = 0.f;
#pragma unroll
        for (int h = 0; h < 16; ++h) s += accp[((size_t)h * 1024 + b) * 32 + t];
        wm[t] = s * (1.0f / 512.0f);
    }
    __syncthreads();
    if (t == 0) {
        float m = wm[0];
        for (int i = 1; i < 32; ++i) m = fmaxf(m, wm[i]);
        float s = 0.f;
        for (int i = 0; i < 32; ++i) { float e = expf(wm[i] - m); ww[i] = e; s += e; }
        float inv = 1.f / s;
        for (int i = 0; i < 32; ++i) ww[i] *= inv;
    }
    __syncthreads();
    for (int d = t; d < 384; d += 128) {
        float v = 0.f;
#pragma unroll
        for (int m = 0; m < 32; ++m) v += ww[m] * exv[((size_t)b * 32 + m) * 384 + d];
        pooled[(size_t)b * 384 + d] = v;
    }
}

// =====================================================================
extern "C" void kernel_launch(void* const* d_in, const int* in_sizes, int n_in,
                              void* d_out, int out_size, void* d_ws, size_t ws_size,
                              hipStream_t stream) {
    const float* h_V    = (const float*)d_in[0];
    const float* h_EXV  = (const float*)d_in[1];
    const float* W_hV   = (const float*)d_in[2];
    const float* b_hV   = (const float*)d_in[3];
    const float* Wq_hv  = (const float*)d_in[4];
    const float* Wk_hv  = (const float*)d_in[5];
    const float* Wq_ce  = (const float*)d_in[6];
    const float* Wk_ce  = (const float*)d_in[7];
    const float* W_ce   = (const float*)d_in[8];
    const float* b_ce   = (const float*)d_in[9];
    const float* Wq_sce = (const float*)d_in[10];
    const float* Wk_sce = (const float*)d_in[11];
    float* out = (float*)d_out;

    char* ws = (char*)d_ws;
    f16*   mt_hv  = (f16*)(ws + 0);           //  2,097,152
    f16*   mt_sce = (f16*)(ws + 2097152);     //  2,097,152
    f16*   mt_ce  = (f16*)(ws + 4194304);     //  4,718,592
    f16*   exv16  = (f16*)(ws + 8912896);     // 25,165,824
    float* hv     = (float*)(ws + 34078720);  //  1,048,576
    float* ce     = (float*)(ws + 35127296);  //  1,048,576
    float* accp   = (float*)(ws + 36175872);  //  2,097,152
    float* pooled = (float*)(ws + 38273024);  //  1,572,864
    float* wpart  = accp;                     // alias: lifetimes ordered

    k_mt<<<dim3(16, 16), 256, 0, stream>>>(Wq_hv, Wk_hv, mt_hv, 256);
    k_mt<<<dim3(16, 36), 256, 0, stream>>>(Wq_ce, Wk_ce, mt_ce, 384);
    k_mt<<<dim3(16, 16), 256, 0, stream>>>(Wq_sce, Wk_sce, mt_sce, 256);
    k_f32_to_f16<<<2048, 256, 0, stream>>>(h_EXV, exv16, 12582912);
    k_lin<<<128, 256, 0, stream>>>(h_V, W_hV, b_hV, hv, 128);
    k_small_int<<<dim3(64, 16), 256, 0, stream>>>(hv, mt_hv, wpart);
    k_small_fin<<<256, 256, 0, stream>>>(wpart, hv, out + 0, out + 65536);
    k_ce_int<<<dim3(512, 16), 512, 74240, stream>>>(exv16, mt_ce, accp);
    k_ce_pool<<<1024, 128, 0, stream>>>(accp, h_EXV, pooled);
    k_lin<<<128, 256, 0, stream>>>(pooled, W_ce, b_ce, ce, 384);
    k_small_int<<<dim3(64, 16), 256, 0, stream>>>(ce, mt_sce, wpart);
    k_small_fin<<<256, 256, 0, stream>>>(wpart, ce, out + 66560, out + 132096);
}

// Round 3
// 385.242 us; speedup vs baseline: 2.6712x; 1.0575x over previous
//
#include <hip/hip_runtime.h>

typedef _Float16 f16;
typedef _Float16 f16x8 __attribute__((ext_vector_type(8)));
typedef _Float16 f16x4v __attribute__((ext_vector_type(4)));
typedef float f32x4 __attribute__((ext_vector_type(4)));

#define MFMA16(a, b, c) __builtin_amdgcn_mfma_f32_16x16x32_f16(a, b, c, 0, 0, 0)

// =====================================================================
// k_mt: M_h = Wq_h^T Wk_h, stored K-blocked:
//   MT[((h*nkk + (e>>5))*H + f)*32 + (e&31)] = sum_d Wq[h*H+d][e]*Wk[h*H+d][f]
// grid (16 heads, (H/64)^2), block 256.
// =====================================================================
__global__ __launch_bounds__(256) void k_mt(const float* __restrict__ Wq,
                                            const float* __restrict__ Wk,
                                            f16* __restrict__ MT, int H) {
    const int h = blockIdx.x;
    const int ntile = H >> 6;
    const int nkk = H >> 5;
    const int frow = (blockIdx.y / ntile) * 64;
    const int ecol = (blockIdx.y % ntile) * 64;
    const int t = threadIdx.x;
    const int lane = t & 63;
    const int w = t >> 6;
    const int wr = w >> 1, wc = w & 1;

    __shared__ __align__(16) f16 As[64][40];
    __shared__ __align__(16) f16 Ks[64][40];

    f32x4 acc[2][2] = {};
    const int d = t >> 3;
    const int e8 = (t & 7) * 8;

    for (int kk = 0; kk < nkk; ++kk) {
        const float* gq = Wq + (size_t)(h * H + kk * 32 + d) * H + ecol + e8;
        const float* gk = Wk + (size_t)(h * H + kk * 32 + d) * H + frow + e8;
        float q[8], k[8];
#pragma unroll
        for (int i = 0; i < 8; ++i) { q[i] = gq[i]; k[i] = gk[i]; }
        __syncthreads();
#pragma unroll
        for (int i = 0; i < 8; ++i) { As[e8 + i][d] = (f16)q[i]; Ks[e8 + i][d] = (f16)k[i]; }
        __syncthreads();
        f16x8 a[2], b[2];
#pragma unroll
        for (int rt = 0; rt < 2; ++rt)
            a[rt] = *(const f16x8*)&Ks[wr * 32 + rt * 16 + (lane & 15)][(lane >> 4) * 8];
#pragma unroll
        for (int nt = 0; nt < 2; ++nt)
            b[nt] = *(const f16x8*)&As[wc * 32 + nt * 16 + (lane & 15)][(lane >> 4) * 8];
#pragma unroll
        for (int rt = 0; rt < 2; ++rt)
#pragma unroll
            for (int nt = 0; nt < 2; ++nt)
                acc[rt][nt] = MFMA16(a[rt], b[nt], acc[rt][nt]);
    }
#pragma unroll
    for (int rt = 0; rt < 2; ++rt)
#pragma unroll
        for (int nt = 0; nt < 2; ++nt)
#pragma unroll
            for (int j = 0; j < 4; ++j) {
                int f = frow + wr * 32 + rt * 16 + (lane >> 4) * 4 + j;
                int e = ecol + wc * 32 + nt * 16 + (lane & 15);
                MT[(((size_t)h * nkk + (e >> 5)) * H + f) * 32 + (e & 31)] = (f16)acc[rt][nt][j];
            }
}

// =====================================================================
__global__ void k_f32_to_f16(const float* __restrict__ in, f16* __restrict__ out, int n) {
    int i = (blockIdx.x * blockDim.x + threadIdx.x) * 4;
    int stride = gridDim.x * blockDim.x * 4;
    for (; i < n; i += stride) {
        float4 v = *(const float4*)(in + i);
        f16x4v o;
        o[0] = (f16)v.x; o[1] = (f16)v.y; o[2] = (f16)v.z; o[3] = (f16)v.w;
        *(f16x4v*)(out + i) = o;
    }
}

// =====================================================================
// k_lin: out[r][j] = sum_d in[r][d]*W[j][d] + b[j], J=256 fixed, 8 rows/block
// =====================================================================
__global__ __launch_bounds__(256) void k_lin(const float* __restrict__ in,
                                             const float* __restrict__ W,
                                             const float* __restrict__ bias,
                                             float* __restrict__ out, int K) {
    const int t = threadIdx.x;
    const int r0 = blockIdx.x * 8;
    __shared__ float ins[8][384];
    __shared__ float Ws[256][33];
#pragma unroll
    for (int r = 0; r < 8; ++r)
        for (int off = t; off < K; off += 256)
            ins[r][off] = in[(size_t)(r0 + r) * K + off];
    float acc[8] = {};
    for (int d0 = 0; d0 < K; d0 += 32) {
        __syncthreads();
        for (int i = t; i < 256 * 32; i += 256) {
            int j = i >> 5, dd = i & 31;
            Ws[j][dd] = W[(size_t)j * K + d0 + dd];
        }
        __syncthreads();
#pragma unroll 8
        for (int dd = 0; dd < 32; ++dd) {
            float wv = Ws[t][dd];
#pragma unroll
            for (int r = 0; r < 8; ++r) acc[r] += wv * ins[r][d0 + dd];
        }
    }
    float bv = bias[t];
#pragma unroll
    for (int r = 0; r < 8; ++r) out[(size_t)(r0 + r) * 256 + t] = acc[r] + bv;
}

// =====================================================================
// k_small_int v2: direct-global M b-frags (prefetched), barrier-free ph1.
// grid (64, 16), block 256 (4 waves). Wave w owns cols w*64+[0,64).
// =====================================================================
__global__ __launch_bounds__(256) void k_small_int(const float* __restrict__ X,
                                                   const f16* __restrict__ MT,
                                                   float* __restrict__ wpart) {
    const int t = threadIdx.x;
    const int lane = t & 63;
    const int w = t >> 6;
    const int g = lane >> 4;
    const int l15 = lane & 15;
    const int pos0 = blockIdx.x * 4;
    const int h = blockIdx.y;

    __shared__ __align__(16) f16 Xs[16][264];
    __shared__ __align__(16) f16 Ts[16][264];

    {
        int row = t >> 4, d0 = (t & 15) * 16;
        int s = row & 3, p = row >> 2;
        const float* gx = X + (size_t)(s * 256 + pos0 + p) * 256 + d0;
#pragma unroll
        for (int i = 0; i < 16; ++i) Xs[row][d0 + i] = (f16)gx[i];
    }
    __syncthreads();

    const f16* mh = MT + (size_t)h * 8 * 256 * 32;
    const int fb = w * 64 + l15;
    f32x4 acc[4] = {};
    f16x8 bq[4], bn[4];
#pragma unroll
    for (int nt = 0; nt < 4; ++nt)
        bq[nt] = *(const f16x8*)(mh + (size_t)(fb + nt * 16) * 32 + g * 8);
#pragma unroll
    for (int kk = 0; kk < 8; ++kk) {
        if (kk < 7) {
#pragma unroll
            for (int nt = 0; nt < 4; ++nt)
                bn[nt] = *(const f16x8*)(mh + ((size_t)(kk + 1) * 256 + fb + nt * 16) * 32 + g * 8);
        }
        f16x8 a = *(const f16x8*)&Xs[l15][kk * 32 + g * 8];
#pragma unroll
        for (int nt = 0; nt < 4; ++nt) acc[nt] = MFMA16(a, bq[nt], acc[nt]);
#pragma unroll
        for (int nt = 0; nt < 4; ++nt) bq[nt] = bn[nt];
    }
#pragma unroll
    for (int nt = 0; nt < 4; ++nt)
#pragma unroll
        for (int j = 0; j < 4; ++j)
            Ts[g * 4 + j][w * 64 + nt * 16 + l15] = (f16)acc[nt][j];
    __syncthreads();
    if (w == 0) {
        f32x4 sacc = {};
#pragma unroll
        for (int ks = 0; ks < 8; ++ks) {
            f16x8 a = *(const f16x8*)&Ts[l15][ks * 32 + g * 8];
            f16x8 b = *(const f16x8*)&Xs[l15][ks * 32 + g * 8];
            sacc = MFMA16(a, b, sacc);
        }
        bool active = (l15 >> 2) == g;
        if (active) {
            const float scale = 1.0f / 16.0f; // 1/sqrt(256)
            float add = 0.f;
#pragma unroll
            for (int j = 0; j < 4; ++j) {
                float v = sacc[j] * scale;
                float m = v;
                m = fmaxf(m, __shfl_xor(m, 1));
                m = fmaxf(m, __shfl_xor(m, 2));
                float e = expf(v - m);
                float s2 = e;
                s2 += __shfl_xor(s2, 1);
                s2 += __shfl_xor(s2, 2);
                add += e / s2;
            }
            int p = g, ms = lane & 3;
            wpart[((size_t)h * 256 + pos0 + p) * 4 + ms] = add;
        }
    }
}

// =====================================================================
// k_small_fin: sum 16 head-partials -> /64 -> softmax(4) -> pool states.
// =====================================================================
__global__ __launch_bounds__(256) void k_small_fin(const float* __restrict__ wpart,
                                                   const float* __restrict__ X,
                                                   float* __restrict__ out_int,
                                                   float* __restrict__ out_w) {
    const int pos = blockIdx.x, t = threadIdx.x;
    __shared__ float red[64];
    __shared__ float ws[4];
    if (t < 64) red[t] = wpart[((size_t)(t >> 2) * 256 + pos) * 4 + (t & 3)];
    __syncthreads();
    if (t == 0) {
        float v[4];
#pragma unroll
        for (int s = 0; s < 4; ++s) {
            float x = 0.f;
            for (int hh = 0; hh < 16; ++hh) x += red[hh * 4 + s];
            v[s] = x * (1.0f / 64.0f);
        }
        float m = fmaxf(fmaxf(v[0], v[1]), fmaxf(v[2], v[3]));
        float sum = 0.f;
#pragma unroll
        for (int s = 0; s < 4; ++s) { v[s] = expf(v[s] - m); sum += v[s]; }
#pragma unroll
        for (int s = 0; s < 4; ++s) ws[s] = v[s] / sum;
    }
    __syncthreads();
    if (t < 4) out_w[pos * 4 + t] = ws[t];
    float v = 0.f;
#pragma unroll
    for (int s = 0; s < 4; ++s) v += ws[s] * X[(size_t)(s * 256 + pos) * 256 + t];
    out_int[(size_t)pos * 256 + t] = v;
}

// =====================================================================
// k_ce_int v3: M direct-from-global (reg-prefetched), barrier-free ph1.
// Wave w owns M cols [w*48, w*48+48), all 64 token-rows. acc[4][3].
// Xs: 64x768B swizzled @ [0,49152). Ts: 64x432B @ [49152,76800).
// grid (512, 16), block 512, dynamic LDS 76800 -> 2 blocks/CU.
// =====================================================================
#define TS_OFF 49152

__global__ __launch_bounds__(512) void k_ce_int(const f16* __restrict__ Xg,
                                                const f16* __restrict__ MT,
                                                float* __restrict__ acc_out) {
    const int t = threadIdx.x;
    const int lane = t & 63;
    const int w = t >> 6;
    const int g = lane >> 4;
    const int l15 = lane & 15;
    const int bg = blockIdx.x;
    const int h = blockIdx.y;

    extern __shared__ __align__(16) char smem[];

    // ---- stage X (64 x 384 f16), source-swizzled, linear LDS ----
    {
        const f16* xg = Xg + (size_t)bg * 64 * 384;
#pragma unroll
        for (int p = 0; p < 6; ++p) {
            int idx = p * 512 + t;
            int row = idx / 48, s = idx - row * 48;
            int c = s ^ (row & 7);
            *(int4*)(smem + idx * 16) = *(const int4*)(xg + row * 384 + c * 8);
        }
    }
    __syncthreads();

    // ---- phase 1: T = X @ M_h (barrier-free; M from global, prefetched) ----
    const f16* mh = MT + (size_t)h * 12 * 384 * 32;
    const int fb = w * 48 + l15;
    f32x4 acc[4][3] = {};
    f16x8 bq[3], bn[3];
#pragma unroll
    for (int nt = 0; nt < 3; ++nt)
        bq[nt] = *(const f16x8*)(mh + (size_t)(fb + nt * 16) * 32 + g * 8);
#pragma unroll
    for (int kk = 0; kk < 12; ++kk) {
        if (kk < 11) {
#pragma unroll
            for (int nt = 0; nt < 3; ++nt)
                bn[nt] = *(const f16x8*)(mh + ((size_t)(kk + 1) * 384 + fb + nt * 16) * 32 + g * 8);
        }
        f16x8 a[4];
#pragma unroll
        for (int rt = 0; rt < 4; ++rt) {
            int row = rt * 16 + l15;
            int ch = kk * 4 + g;
            a[rt] = *(const f16x8*)(smem + row * 768 + ((ch ^ (row & 7)) << 4));
        }
#pragma unroll
        for (int rt = 0; rt < 4; ++rt)
#pragma unroll
            for (int nt = 0; nt < 3; ++nt)
                acc[rt][nt] = MFMA16(a[rt], bq[nt], acc[rt][nt]);
#pragma unroll
        for (int nt = 0; nt < 3; ++nt) bq[nt] = bn[nt];
    }

    // ---- phase 2: S_b = T_b @ X_b^T over e' in two 192-col halves of Ts ----
    f32x4 s2[2][2] = {};
    const int b = w;  // used by waves 0,1

    // half 0: waves 0-3 publish cols [0,192)
    if (w < 4) {
        int flb = w * 48 + l15;
#pragma unroll
        for (int rt = 0; rt < 4; ++rt)
#pragma unroll
            for (int nt = 0; nt < 3; ++nt)
#pragma unroll
                for (int j = 0; j < 4; ++j) {
                    int l = rt * 16 + g * 4 + j;
                    *(f16*)(smem + TS_OFF + l * 432 + (flb + nt * 16) * 2) = (f16)acc[rt][nt][j];
                }
    }
    __syncthreads();
    if (w < 2) {
#pragma unroll
        for (int ks = 0; ks < 6; ++ks) {
            f16x8 a2[2], b2[2];
#pragma unroll
            for (int lt = 0; lt < 2; ++lt) {
                int l = b * 32 + lt * 16 + l15;
                a2[lt] = *(const f16x8*)(smem + TS_OFF + l * 432 + (ks * 32 + g * 8) * 2);
            }
#pragma unroll
            for (int nt = 0; nt < 2; ++nt) {
                int row = b * 32 + nt * 16 + l15;
                int ch = ks * 4 + g;
                b2[nt] = *(const f16x8*)(smem + row * 768 + ((ch ^ (row & 7)) << 4));
            }
#pragma unroll
            for (int lt = 0; lt < 2; ++lt)
#pragma unroll
                for (int nt = 0; nt < 2; ++nt)
                    s2[lt][nt] = MFMA16(a2[lt], b2[nt], s2[lt][nt]);
        }
    }
    __syncthreads();
    // half 1: waves 4-7 publish cols [192,384)
    if (w >= 4) {
        int flb = (w - 4) * 48 + l15;
#pragma unroll
        for (int rt = 0; rt < 4; ++rt)
#pragma unroll
            for (int nt = 0; nt < 3; ++nt)
#pragma unroll
                for (int j = 0; j < 4; ++j) {
                    int l = rt * 16 + g * 4 + j;
                    *(f16*)(smem + TS_OFF + l * 432 + (flb + nt * 16) * 2) = (f16)acc[rt][nt][j];
                }
    }
    __syncthreads();
    if (w < 2) {
#pragma unroll
        for (int ks = 0; ks < 6; ++ks) {
            f16x8 a2[2], b2[2];
#pragma unroll
            for (int lt = 0; lt < 2; ++lt) {
                int l = b * 32 + lt * 16 + l15;
                a2[lt] = *(const f16x8*)(smem + TS_OFF + l * 432 + (ks * 32 + g * 8) * 2);
            }
#pragma unroll
            for (int nt = 0; nt < 2; ++nt) {
                int row = b * 32 + nt * 16 + l15;
                int ch = (6 + ks) * 4 + g;
                b2[nt] = *(const f16x8*)(smem + row * 768 + ((ch ^ (row & 7)) << 4));
            }
#pragma unroll
            for (int lt = 0; lt < 2; ++lt)
#pragma unroll
                for (int nt = 0; nt < 2; ++nt)
                    s2[lt][nt] = MFMA16(a2[lt], b2[nt], s2[lt][nt]);
        }

        // ---- softmax rows + column sums, direct global write ----
        const float scale = 0.051031036307982884f; // 1/sqrt(384)
        float cp0 = 0.f, cp1 = 0.f;
#pragma unroll
        for (int lt = 0; lt < 2; ++lt)
#pragma unroll
            for (int j = 0; j < 4; ++j) {
                float v0 = s2[lt][0][j] * scale;
                float v1 = s2[lt][1][j] * scale;
                float m = fmaxf(v0, v1);
                m = fmaxf(m, __shfl_xor(m, 1));
                m = fmaxf(m, __shfl_xor(m, 2));
                m = fmaxf(m, __shfl_xor(m, 4));
                m = fmaxf(m, __shfl_xor(m, 8));
                float e0 = expf(v0 - m), e1 = expf(v1 - m);
                float s = e0 + e1;
                s += __shfl_xor(s, 1);
                s += __shfl_xor(s, 2);
                s += __shfl_xor(s, 4);
                s += __shfl_xor(s, 8);
                float inv = 1.f / s;
                cp0 += e0 * inv;
                cp1 += e1 * inv;
            }
        cp0 += __shfl_xor(cp0, 16); cp0 += __shfl_xor(cp0, 32);
        cp1 += __shfl_xor(cp1, 16); cp1 += __shfl_xor(cp1, 32);
        if (lane < 16) {
            float* o = acc_out + ((size_t)h * 1024 + bg * 2 + b) * 32;
            o[lane] = cp0;
            o[16 + lane] = cp1;
        }
    }
}

// =====================================================================
// k_ce_pool: w = softmax(sum_h accp / 512); pooled[b] = sum_m w[m]*exv[b][m][:]
// =====================================================================
__global__ __launch_bounds__(128) void k_ce_pool(const float* __restrict__ accp,
                                                 const float* __restrict__ exv,
                                                 float* __restrict__ pooled) {
    const int b = blockIdx.x;
    const int t = threadIdx.x;
    __shared__ float wm[32];
    __shared__ float ww[32];
    if (t < 32) {
        float s = 0.f;
#pragma unroll
        for (int h = 0; h < 16; ++h) s += accp[((size_t)h * 1024 + b) * 32 + t];
        wm[t] = s * (1.0f / 512.0f);
    }
    __syncthreads();
    if (t == 0) {
        float m = wm[0];
        for (int i = 1; i < 32; ++i) m = fmaxf(m, wm[i]);
        float s = 0.f;
        for (int i = 0; i < 32; ++i) { float e = expf(wm[i] - m); ww[i] = e; s += e; }
        float inv = 1.f / s;
        for (int i = 0; i < 32; ++i) ww[i] *= inv;
    }
    __syncthreads();
    for (int d = t; d < 384; d += 128) {
        float v = 0.f;
#pragma unroll
        for (int m = 0; m < 32; ++m) v += ww[m] * exv[((size_t)b * 32 + m) * 384 + d];
        pooled[(size_t)b * 384 + d] = v;
    }
}

// =====================================================================
extern "C" void kernel_launch(void* const* d_in, const int* in_sizes, int n_in,
                              void* d_out, int out_size, void* d_ws, size_t ws_size,
                              hipStream_t stream) {
    const float* h_V    = (const float*)d_in[0];
    const float* h_EXV  = (const float*)d_in[1];
    const float* W_hV   = (const float*)d_in[2];
    const float* b_hV   = (const float*)d_in[3];
    const float* Wq_hv  = (const float*)d_in[4];
    const float* Wk_hv  = (const float*)d_in[5];
    const float* Wq_ce  = (const float*)d_in[6];
    const float* Wk_ce  = (const float*)d_in[7];
    const float* W_ce   = (const float*)d_in[8];
    const float* b_ce   = (const float*)d_in[9];
    const float* Wq_sce = (const float*)d_in[10];
    const float* Wk_sce = (const float*)d_in[11];
    float* out = (float*)d_out;

    char* ws = (char*)d_ws;
    f16*   mt_hv  = (f16*)(ws + 0);           //  2,097,152
    f16*   mt_sce = (f16*)(ws + 2097152);     //  2,097,152
    f16*   mt_ce  = (f16*)(ws + 4194304);     //  4,718,592
    f16*   exv16  = (f16*)(ws + 8912896);     // 25,165,824
    float* hv     = (float*)(ws + 34078720);  //  1,048,576
    float* ce     = (float*)(ws + 35127296);  //  1,048,576
    float* accp   = (float*)(ws + 36175872);  //  2,097,152
    float* pooled = (float*)(ws + 38273024);  //  1,572,864
    float* wpart  = accp;                     // alias: lifetimes ordered

    k_mt<<<dim3(16, 16), 256, 0, stream>>>(Wq_hv, Wk_hv, mt_hv, 256);
    k_mt<<<dim3(16, 36), 256, 0, stream>>>(Wq_ce, Wk_ce, mt_ce, 384);
    k_mt<<<dim3(16, 16), 256, 0, stream>>>(Wq_sce, Wk_sce, mt_sce, 256);
    k_f32_to_f16<<<2048, 256, 0, stream>>>(h_EXV, exv16, 12582912);
    k_lin<<<128, 256, 0, stream>>>(h_V, W_hV, b_hV, hv, 128);
    k_small_int<<<dim3(64, 16), 256, 0, stream>>>(hv, mt_hv, wpart);
    k_small_fin<<<256, 256, 0, stream>>>(wpart, hv, out + 0, out + 65536);
    k_ce_int<<<dim3(512, 16), 512, 76800, stream>>>(exv16, mt_ce, accp);
    k_ce_pool<<<1024, 128, 0, stream>>>(accp, h_EXV, pooled);
    k_lin<<<128, 256, 0, stream>>>(pooled, W_ce, b_ce, ce, 384);
    k_small_int<<<dim3(64, 16), 256, 0, stream>>>(ce, mt_sce, wpart);
    k_small_fin<<<256, 256, 0, stream>>>(wpart, ce, out + 66560, out + 132096);
}

// Round 4
// 349.028 us; speedup vs baseline: 2.9484x; 1.1038x over previous
//
#include <hip/hip_runtime.h>

typedef _Float16 f16;
typedef _Float16 f16x8 __attribute__((ext_vector_type(8)));
typedef float f32x4 __attribute__((ext_vector_type(4)));

#define MFMA16(a, b, c) __builtin_amdgcn_mfma_f32_16x16x32_f16(a, b, c, 0, 0, 0)

// =====================================================================
// k_mt: M_h = Wq_h^T Wk_h, stored K-blocked:
//   MT[((h*nkk + (e>>5))*H + f)*32 + (e&31)] = sum_d Wq[h*H+d][e]*Wk[h*H+d][f]
// =====================================================================
__global__ __launch_bounds__(256) void k_mt(const float* __restrict__ Wq,
                                            const float* __restrict__ Wk,
                                            f16* __restrict__ MT, int H) {
    const int h = blockIdx.x;
    const int ntile = H >> 6;
    const int nkk = H >> 5;
    const int frow = (blockIdx.y / ntile) * 64;
    const int ecol = (blockIdx.y % ntile) * 64;
    const int t = threadIdx.x;
    const int lane = t & 63;
    const int w = t >> 6;
    const int wr = w >> 1, wc = w & 1;

    __shared__ __align__(16) f16 As[64][40];
    __shared__ __align__(16) f16 Ks[64][40];

    f32x4 acc[2][2] = {};
    const int d = t >> 3;
    const int e8 = (t & 7) * 8;

    for (int kk = 0; kk < nkk; ++kk) {
        const float* gq = Wq + (size_t)(h * H + kk * 32 + d) * H + ecol + e8;
        const float* gk = Wk + (size_t)(h * H + kk * 32 + d) * H + frow + e8;
        float q[8], k[8];
#pragma unroll
        for (int i = 0; i < 8; ++i) { q[i] = gq[i]; k[i] = gk[i]; }
        __syncthreads();
#pragma unroll
        for (int i = 0; i < 8; ++i) { As[e8 + i][d] = (f16)q[i]; Ks[e8 + i][d] = (f16)k[i]; }
        __syncthreads();
        f16x8 a[2], b[2];
#pragma unroll
        for (int rt = 0; rt < 2; ++rt)
            a[rt] = *(const f16x8*)&Ks[wr * 32 + rt * 16 + (lane & 15)][(lane >> 4) * 8];
#pragma unroll
        for (int nt = 0; nt < 2; ++nt)
            b[nt] = *(const f16x8*)&As[wc * 32 + nt * 16 + (lane & 15)][(lane >> 4) * 8];
#pragma unroll
        for (int rt = 0; rt < 2; ++rt)
#pragma unroll
            for (int nt = 0; nt < 2; ++nt)
                acc[rt][nt] = MFMA16(a[rt], b[nt], acc[rt][nt]);
    }
#pragma unroll
    for (int rt = 0; rt < 2; ++rt)
#pragma unroll
        for (int nt = 0; nt < 2; ++nt)
#pragma unroll
            for (int j = 0; j < 4; ++j) {
                int f = frow + wr * 32 + rt * 16 + (lane >> 4) * 4 + j;
                int e = ecol + wc * 32 + nt * 16 + (lane & 15);
                MT[(((size_t)h * nkk + (e >> 5)) * H + f) * 32 + (e & 31)] = (f16)acc[rt][nt][j];
            }
}

// =====================================================================
// k_lin: out[r][j] = sum_d in[r][d]*W[j][d] + b[j], J=256, 4 rows/block.
// grid 256.
// =====================================================================
__global__ __launch_bounds__(256) void k_lin(const float* __restrict__ in,
                                             const float* __restrict__ W,
                                             const float* __restrict__ bias,
                                             float* __restrict__ out, int K) {
    const int t = threadIdx.x;
    const int r0 = blockIdx.x * 4;
    __shared__ float ins[4][384];
    __shared__ float Ws[256][33];
#pragma unroll
    for (int r = 0; r < 4; ++r)
        for (int off = t; off < K; off += 256)
            ins[r][off] = in[(size_t)(r0 + r) * K + off];
    float acc[4] = {};
    for (int d0 = 0; d0 < K; d0 += 32) {
        __syncthreads();
        for (int i = t; i < 256 * 32; i += 256) {
            int j = i >> 5, dd = i & 31;
            Ws[j][dd] = W[(size_t)j * K + d0 + dd];
        }
        __syncthreads();
#pragma unroll 8
        for (int dd = 0; dd < 32; ++dd) {
            float wv = Ws[t][dd];
#pragma unroll
            for (int r = 0; r < 4; ++r) acc[r] += wv * ins[r][d0 + dd];
        }
    }
    float bv = bias[t];
#pragma unroll
    for (int r = 0; r < 4; ++r) out[(size_t)(r0 + r) * 256 + t] = acc[r] + bv;
}

// =====================================================================
// k_small_int v3: 16 pos-groups/block (64 X-rows), all-wave phase 2.
// X layout [4 states][256 pos][256]. LDS row = p_local*4 + s.
// grid (16, 16), block 256, dynamic LDS 67584.
// =====================================================================
__global__ __launch_bounds__(256) void k_small_int(const float* __restrict__ X,
                                                   const f16* __restrict__ MT,
                                                   float* __restrict__ wpart) {
    const int t = threadIdx.x;
    const int lane = t & 63;
    const int w = t >> 6;
    const int g = lane >> 4;
    const int l15 = lane & 15;
    const int pos0 = blockIdx.x * 16;
    const int h = blockIdx.y;

    extern __shared__ __align__(16) char smem0[];
    f16(*Xs)[264] = (f16(*)[264])smem0;                  // 33792 B
    f16(*Ts)[264] = (f16(*)[264])(smem0 + 33792);        // 33792 B

    {
        int row = t >> 2, d0 = (t & 3) * 64;
        int s = row & 3, p = row >> 2;
        const float* gx = X + (size_t)(s * 256 + pos0 + p) * 256 + d0;
#pragma unroll
        for (int i = 0; i < 8; ++i) {
            float4 v0 = *(const float4*)(gx + i * 8);
            float4 v1 = *(const float4*)(gx + i * 8 + 4);
            f16x8 o;
            o[0] = (f16)v0.x; o[1] = (f16)v0.y; o[2] = (f16)v0.z; o[3] = (f16)v0.w;
            o[4] = (f16)v1.x; o[5] = (f16)v1.y; o[6] = (f16)v1.z; o[7] = (f16)v1.w;
            *(f16x8*)&Xs[row][d0 + i * 8] = o;
        }
    }
    __syncthreads();

    // phase 1: T = X(64x256) @ M_h; wave w owns cols w*64+[0,64)
    const f16* mh = MT + (size_t)h * 8 * 256 * 32;
    const int fb = w * 64 + l15;
    f32x4 acc[4][4] = {};
    f16x8 bq[4], bn[4];
#pragma unroll
    for (int nt = 0; nt < 4; ++nt)
        bq[nt] = *(const f16x8*)(mh + (size_t)(fb + nt * 16) * 32 + g * 8);
#pragma unroll
    for (int kk = 0; kk < 8; ++kk) {
        if (kk < 7) {
#pragma unroll
            for (int nt = 0; nt < 4; ++nt)
                bn[nt] = *(const f16x8*)(mh + ((size_t)(kk + 1) * 256 + fb + nt * 16) * 32 + g * 8);
        }
        f16x8 a[4];
#pragma unroll
        for (int rt = 0; rt < 4; ++rt)
            a[rt] = *(const f16x8*)&Xs[rt * 16 + l15][kk * 32 + g * 8];
#pragma unroll
        for (int rt = 0; rt < 4; ++rt)
#pragma unroll
            for (int nt = 0; nt < 4; ++nt)
                acc[rt][nt] = MFMA16(a[rt], bq[nt], acc[rt][nt]);
#pragma unroll
        for (int nt = 0; nt < 4; ++nt) bq[nt] = bn[nt];
    }
#pragma unroll
    for (int rt = 0; rt < 4; ++rt)
#pragma unroll
        for (int nt = 0; nt < 4; ++nt)
#pragma unroll
            for (int j = 0; j < 4; ++j)
                Ts[rt * 16 + g * 4 + j][w * 64 + nt * 16 + l15] = (f16)acc[rt][nt][j];
    __syncthreads();

    // phase 2: wave w computes S tile [16w,16w+16)^2 over K=256
    f32x4 sacc = {};
#pragma unroll
    for (int ks = 0; ks < 8; ++ks) {
        f16x8 a = *(const f16x8*)&Ts[w * 16 + l15][ks * 32 + g * 8];
        f16x8 b = *(const f16x8*)&Xs[w * 16 + l15][ks * 32 + g * 8];
        sacc = MFMA16(a, b, sacc);
    }
    if ((l15 >> 2) == g) {
        const float scale = 1.0f / 16.0f; // 1/sqrt(256)
        float add = 0.f;
#pragma unroll
        for (int j = 0; j < 4; ++j) {
            float v = sacc[j] * scale;
            float m = v;
            m = fmaxf(m, __shfl_xor(m, 1));
            m = fmaxf(m, __shfl_xor(m, 2));
            float e = expf(v - m);
            float s2 = e;
            s2 += __shfl_xor(s2, 1);
            s2 += __shfl_xor(s2, 2);
            add += e / s2;
        }
        int pg = pos0 + w * 4 + g;
        wpart[((size_t)h * 256 + pg) * 4 + (l15 & 3)] = add;
    }
}

// =====================================================================
// k_small_fin: sum 16 head-partials -> /64 -> softmax(4) -> pool states.
// =====================================================================
__global__ __launch_bounds__(256) void k_small_fin(const float* __restrict__ wpart,
                                                   const float* __restrict__ X,
                                                   float* __restrict__ out_int,
                                                   float* __restrict__ out_w) {
    const int pos = blockIdx.x, t = threadIdx.x;
    __shared__ float red[64];
    __shared__ float ws[4];
    if (t < 64) red[t] = wpart[((size_t)(t >> 2) * 256 + pos) * 4 + (t & 3)];
    __syncthreads();
    if (t == 0) {
        float v[4];
#pragma unroll
        for (int s = 0; s < 4; ++s) {
            float x = 0.f;
            for (int hh = 0; hh < 16; ++hh) x += red[hh * 4 + s];
            v[s] = x * (1.0f / 64.0f);
        }
        float m = fmaxf(fmaxf(v[0], v[1]), fmaxf(v[2], v[3]));
        float sum = 0.f;
#pragma unroll
        for (int s = 0; s < 4; ++s) { v[s] = expf(v[s] - m); sum += v[s]; }
#pragma unroll
        for (int s = 0; s < 4; ++s) ws[s] = v[s] / sum;
    }
    __syncthreads();
    if (t < 4) out_w[pos * 4 + t] = ws[t];
    float v = 0.f;
#pragma unroll
    for (int s = 0; s < 4; ++s) v += ws[s] * X[(size_t)(s * 256 + pos) * 256 + t];
    out_int[(size_t)pos * 256 + t] = v;
}

// =====================================================================
// k_ce_int v4: 4 waves x 96 M-cols, 4 heads/block, fused f32->f16 staging,
// all-wave phase 2 via Ts thirds.
// Xg32: [32768 tok][384] f32. MT: [16][12][384][32] f16. acc_out [16][1024][32].
// grid (512, 4), block 256, dynamic LDS 67072 -> 2 blocks/CU.
// =====================================================================
#define TS_OFF 49152
#define AP_OFF 66560

__global__ __launch_bounds__(256, 2) void k_ce_int(const float* __restrict__ Xg32,
                                                   const f16* __restrict__ MT,
                                                   float* __restrict__ acc_out) {
    const int t = threadIdx.x;
    const int lane = t & 63;
    const int w = t >> 6;
    const int g = lane >> 4;
    const int l15 = lane & 15;
    const int bg = blockIdx.x;

    extern __shared__ __align__(16) char smem[];
    float* ap = (float*)(smem + AP_OFF);

    // ---- stage X (64 x 384), f32 -> f16, source-swizzled, linear LDS ----
    {
        const float* xg = Xg32 + (size_t)bg * 64 * 384;
#pragma unroll
        for (int p = 0; p < 12; ++p) {
            int idx = p * 256 + t;
            int row = idx / 48, s = idx - row * 48;
            int c = s ^ (row & 7);
            const float* src = xg + row * 384 + c * 8;
            float4 v0 = *(const float4*)src;
            float4 v1 = *(const float4*)(src + 4);
            f16x8 o;
            o[0] = (f16)v0.x; o[1] = (f16)v0.y; o[2] = (f16)v0.z; o[3] = (f16)v0.w;
            o[4] = (f16)v1.x; o[5] = (f16)v1.y; o[6] = (f16)v1.z; o[7] = (f16)v1.w;
            *(f16x8*)(smem + idx * 16) = o;
        }
    }
    __syncthreads();

    for (int hi = 0; hi < 4; ++hi) {
        const int h = blockIdx.y * 4 + hi;
        const f16* mh = MT + (size_t)h * 12 * 384 * 32;

        // ---- phase 1: T = X @ M_h; wave w owns cols w*96+[0,96) ----
        f32x4 acc[4][6] = {};
        f16x8 bq[6], bn[6];
#pragma unroll
        for (int nt = 0; nt < 6; ++nt)
            bq[nt] = *(const f16x8*)(mh + (size_t)(w * 96 + nt * 16 + l15) * 32 + g * 8);
#pragma unroll
        for (int kk = 0; kk < 12; ++kk) {
            if (kk < 11) {
#pragma unroll
                for (int nt = 0; nt < 6; ++nt)
                    bn[nt] = *(const f16x8*)(mh + ((size_t)(kk + 1) * 384 + w * 96 + nt * 16 + l15) * 32 + g * 8);
            }
            f16x8 a[4];
#pragma unroll
            for (int rt = 0; rt < 4; ++rt) {
                int row = rt * 16 + l15;
                int ch = kk * 4 + g;
                a[rt] = *(const f16x8*)(smem + row * 768 + ((ch ^ (row & 7)) << 4));
            }
#pragma unroll
            for (int rt = 0; rt < 4; ++rt)
#pragma unroll
                for (int nt = 0; nt < 6; ++nt)
                    acc[rt][nt] = MFMA16(a[rt], bq[nt], acc[rt][nt]);
#pragma unroll
            for (int nt = 0; nt < 6; ++nt) bq[nt] = bn[nt];
        }

        // ---- phase 2: S_b = T_b @ X_b^T, Ts published in 3 thirds ----
        const int b = w >> 1, lt = w & 1;
        f32x4 s2[2] = {};
#pragma unroll
        for (int c = 0; c < 3; ++c) {
#pragma unroll
            for (int nt = 0; nt < 6; ++nt) {
                int col0 = w * 96 + nt * 16;
                if ((col0 >> 7) == c) {
#pragma unroll
                    for (int rt = 0; rt < 4; ++rt)
#pragma unroll
                        for (int j = 0; j < 4; ++j) {
                            int l = rt * 16 + g * 4 + j;
                            int cl = col0 + l15 - c * 128;
                            *(f16*)(smem + TS_OFF + l * 272 + cl * 2) = (f16)acc[rt][nt][j];
                        }
                }
            }
            __syncthreads();
#pragma unroll
            for (int ks = 0; ks < 4; ++ks) {
                int l = b * 32 + lt * 16 + l15;
                f16x8 a2 = *(const f16x8*)(smem + TS_OFF + l * 272 + (ks * 32 + g * 8) * 2);
#pragma unroll
                for (int nt2 = 0; nt2 < 2; ++nt2) {
                    int m = b * 32 + nt2 * 16 + l15;
                    int ch = c * 16 + ks * 4 + g;
                    f16x8 b2 = *(const f16x8*)(smem + m * 768 + ((ch ^ (m & 7)) << 4));
                    s2[nt2] = MFMA16(a2, b2, s2[nt2]);
                }
            }
            __syncthreads();
        }

        // ---- softmax rows (intra-wave) + column partial sums ----
        const float scale = 0.051031036307982884f; // 1/sqrt(384)
        float cp0 = 0.f, cp1 = 0.f;
#pragma unroll
        for (int j = 0; j < 4; ++j) {
            float v0 = s2[0][j] * scale, v1 = s2[1][j] * scale;
            float m = fmaxf(v0, v1);
            m = fmaxf(m, __shfl_xor(m, 1));
            m = fmaxf(m, __shfl_xor(m, 2));
            m = fmaxf(m, __shfl_xor(m, 4));
            m = fmaxf(m, __shfl_xor(m, 8));
            float e0 = expf(v0 - m), e1 = expf(v1 - m);
            float s = e0 + e1;
            s += __shfl_xor(s, 1);
            s += __shfl_xor(s, 2);
            s += __shfl_xor(s, 4);
            s += __shfl_xor(s, 8);
            float inv = 1.f / s;
            cp0 += e0 * inv;
            cp1 += e1 * inv;
        }
        cp0 += __shfl_xor(cp0, 16); cp0 += __shfl_xor(cp0, 32);
        cp1 += __shfl_xor(cp1, 16); cp1 += __shfl_xor(cp1, 32);
        if (lane < 16) {
            ap[w * 32 + lane] = cp0;
            ap[w * 32 + 16 + lane] = cp1;
        }
        __syncthreads();
        if (t < 64) {
            int bb = t >> 5, m = t & 31;
            float v = ap[bb * 64 + m] + ap[bb * 64 + 32 + m];
            acc_out[((size_t)h * 1024 + bg * 2 + bb) * 32 + m] = v;
        }
        __syncthreads();
    }
}

// =====================================================================
// k_ce_pool: w = softmax(sum_h accp / 512); pooled[b] = sum_m w[m]*exv[b][m][:]
// =====================================================================
__global__ __launch_bounds__(128) void k_ce_pool(const float* __restrict__ accp,
                                                 const float* __restrict__ exv,
                                                 float* __restrict__ pooled) {
    const int b = blockIdx.x;
    const int t = threadIdx.x;
    __shared__ float wm[32];
    __shared__ float ww[32];
    if (t < 32) {
        float s = 0.f;
#pragma unroll
        for (int h = 0; h < 16; ++h) s += accp[((size_t)h * 1024 + b) * 32 + t];
        wm[t] = s * (1.0f / 512.0f);
    }
    __syncthreads();
    if (t == 0) {
        float m = wm[0];
        for (int i = 1; i < 32; ++i) m = fmaxf(m, wm[i]);
        float s = 0.f;
        for (int i = 0; i < 32; ++i) { float e = expf(wm[i] - m); ww[i] = e; s += e; }
        float inv = 1.f / s;
        for (int i = 0; i < 32; ++i) ww[i] *= inv;
    }
    __syncthreads();
    for (int d = t; d < 384; d += 128) {
        float v = 0.f;
#pragma unroll
        for (int m = 0; m < 32; ++m) v += ww[m] * exv[((size_t)b * 32 + m) * 384 + d];
        pooled[(size_t)b * 384 + d] = v;
    }
}

// =====================================================================
extern "C" void kernel_launch(void* const* d_in, const int* in_sizes, int n_in,
                              void* d_out, int out_size, void* d_ws, size_t ws_size,
                              hipStream_t stream) {
    const float* h_V    = (const float*)d_in[0];
    const float* h_EXV  = (const float*)d_in[1];
    const float* W_hV   = (const float*)d_in[2];
    const float* b_hV   = (const float*)d_in[3];
    const float* Wq_hv  = (const float*)d_in[4];
    const float* Wk_hv  = (const float*)d_in[5];
    const float* Wq_ce  = (const float*)d_in[6];
    const float* Wk_ce  = (const float*)d_in[7];
    const float* W_ce   = (const float*)d_in[8];
    const float* b_ce   = (const float*)d_in[9];
    const float* Wq_sce = (const float*)d_in[10];
    const float* Wk_sce = (const float*)d_in[11];
    float* out = (float*)d_out;

    char* ws = (char*)d_ws;
    f16*   mt_hv  = (f16*)(ws + 0);           //  2,097,152
    f16*   mt_sce = (f16*)(ws + 2097152);     //  2,097,152
    f16*   mt_ce  = (f16*)(ws + 4194304);     //  4,718,592
    float* hv     = (float*)(ws + 8912896);   //  1,048,576
    float* ce     = (float*)(ws + 9961472);   //  1,048,576
    float* accp   = (float*)(ws + 11010048);  //  2,097,152
    float* pooled = (float*)(ws + 13107200);  //  1,572,864  (total ~14.7 MB)
    float* wpart  = accp;                     // alias: lifetimes ordered

    k_mt<<<dim3(16, 16), 256, 0, stream>>>(Wq_hv, Wk_hv, mt_hv, 256);
    k_mt<<<dim3(16, 36), 256, 0, stream>>>(Wq_ce, Wk_ce, mt_ce, 384);
    k_mt<<<dim3(16, 16), 256, 0, stream>>>(Wq_sce, Wk_sce, mt_sce, 256);
    k_lin<<<256, 256, 0, stream>>>(h_V, W_hV, b_hV, hv, 128);
    k_small_int<<<dim3(16, 16), 256, 67584, stream>>>(hv, mt_hv, wpart);
    k_small_fin<<<256, 256, 0, stream>>>(wpart, hv, out + 0, out + 65536);
    k_ce_int<<<dim3(512, 4), 256, 67072, stream>>>(h_EXV, mt_ce, accp);
    k_ce_pool<<<1024, 128, 0, stream>>>(accp, h_EXV, pooled);
    k_lin<<<256, 256, 0, stream>>>(pooled, W_ce, b_ce, ce, 384);
    k_small_int<<<dim3(16, 16), 256, 67584, stream>>>(ce, mt_sce, wpart);
    k_small_fin<<<256, 256, 0, stream>>>(wpart, ce, out + 66560, out + 132096);
}

// Round 5
// 328.916 us; speedup vs baseline: 3.1287x; 1.0611x over previous
//
#include <hip/hip_runtime.h>

typedef _Float16 f16;
typedef _Float16 f16x8 __attribute__((ext_vector_type(8)));
typedef _Float16 f16x4 __attribute__((ext_vector_type(4)));
typedef float f32x4 __attribute__((ext_vector_type(4)));

#define MFMA16(a, b, c) __builtin_amdgcn_mfma_f32_16x16x32_f16(a, b, c, 0, 0, 0)
#define MFMA16K16(a, b, c) __builtin_amdgcn_mfma_f32_16x16x16f16(a, b, c, 0, 0, 0)

// =====================================================================
// k_mt: M_h = Wq_h^T Wk_h, stored K-blocked:
//   MT[((h*nkk + (e>>5))*H + f)*32 + (e&31)] = sum_d Wq[h*H+d][e]*Wk[h*H+d][f]
// =====================================================================
__global__ __launch_bounds__(256) void k_mt(const float* __restrict__ Wq,
                                            const float* __restrict__ Wk,
                                            f16* __restrict__ MT, int H) {
    const int h = blockIdx.x;
    const int ntile = H >> 6;
    const int nkk = H >> 5;
    const int frow = (blockIdx.y / ntile) * 64;
    const int ecol = (blockIdx.y % ntile) * 64;
    const int t = threadIdx.x;
    const int lane = t & 63;
    const int w = t >> 6;
    const int wr = w >> 1, wc = w & 1;

    __shared__ __align__(16) f16 As[64][40];
    __shared__ __align__(16) f16 Ks[64][40];

    f32x4 acc[2][2] = {};
    const int d = t >> 3;
    const int e8 = (t & 7) * 8;

    for (int kk = 0; kk < nkk; ++kk) {
        const float* gq = Wq + (size_t)(h * H + kk * 32 + d) * H + ecol + e8;
        const float* gk = Wk + (size_t)(h * H + kk * 32 + d) * H + frow + e8;
        float q[8], k[8];
#pragma unroll
        for (int i = 0; i < 8; ++i) { q[i] = gq[i]; k[i] = gk[i]; }
        __syncthreads();
#pragma unroll
        for (int i = 0; i < 8; ++i) { As[e8 + i][d] = (f16)q[i]; Ks[e8 + i][d] = (f16)k[i]; }
        __syncthreads();
        f16x8 a[2], b[2];
#pragma unroll
        for (int rt = 0; rt < 2; ++rt)
            a[rt] = *(const f16x8*)&Ks[wr * 32 + rt * 16 + (lane & 15)][(lane >> 4) * 8];
#pragma unroll
        for (int nt = 0; nt < 2; ++nt)
            b[nt] = *(const f16x8*)&As[wc * 32 + nt * 16 + (lane & 15)][(lane >> 4) * 8];
#pragma unroll
        for (int rt = 0; rt < 2; ++rt)
#pragma unroll
            for (int nt = 0; nt < 2; ++nt)
                acc[rt][nt] = MFMA16(a[rt], b[nt], acc[rt][nt]);
    }
#pragma unroll
    for (int rt = 0; rt < 2; ++rt)
#pragma unroll
        for (int nt = 0; nt < 2; ++nt)
#pragma unroll
            for (int j = 0; j < 4; ++j) {
                int f = frow + wr * 32 + rt * 16 + (lane >> 4) * 4 + j;
                int e = ecol + wc * 32 + nt * 16 + (lane & 15);
                MT[(((size_t)h * nkk + (e >> 5)) * H + f) * 32 + (e & 31)] = (f16)acc[rt][nt][j];
            }
}

// =====================================================================
// k_lin: out[r][j] = sum_d in[r][d]*W[j][d] + b[j], J=256, 4 rows/block.
// =====================================================================
__global__ __launch_bounds__(256) void k_lin(const float* __restrict__ in,
                                             const float* __restrict__ W,
                                             const float* __restrict__ bias,
                                             float* __restrict__ out, int K) {
    const int t = threadIdx.x;
    const int r0 = blockIdx.x * 4;
    __shared__ float ins[4][384];
    __shared__ float Ws[256][33];
#pragma unroll
    for (int r = 0; r < 4; ++r)
        for (int off = t; off < K; off += 256)
            ins[r][off] = in[(size_t)(r0 + r) * K + off];
    float acc[4] = {};
    for (int d0 = 0; d0 < K; d0 += 32) {
        __syncthreads();
        for (int i = t; i < 256 * 32; i += 256) {
            int j = i >> 5, dd = i & 31;
            Ws[j][dd] = W[(size_t)j * K + d0 + dd];
        }
        __syncthreads();
#pragma unroll 8
        for (int dd = 0; dd < 32; ++dd) {
            float wv = Ws[t][dd];
#pragma unroll
            for (int r = 0; r < 4; ++r) acc[r] += wv * ins[r][d0 + dd];
        }
    }
    float bv = bias[t];
#pragma unroll
    for (int r = 0; r < 4; ++r) out[(size_t)(r0 + r) * 256 + t] = acc[r] + bv;
}

// =====================================================================
// k_small_int: 16 pos-groups/block (64 X-rows), all-wave phase 2.
// grid (16, 16), block 256, dynamic LDS 67584.
// =====================================================================
__global__ __launch_bounds__(256) void k_small_int(const float* __restrict__ X,
                                                   const f16* __restrict__ MT,
                                                   float* __restrict__ wpart) {
    const int t = threadIdx.x;
    const int lane = t & 63;
    const int w = t >> 6;
    const int g = lane >> 4;
    const int l15 = lane & 15;
    const int pos0 = blockIdx.x * 16;
    const int h = blockIdx.y;

    extern __shared__ __align__(16) char smem0[];
    f16(*Xs)[264] = (f16(*)[264])smem0;                  // 33792 B
    f16(*Ts)[264] = (f16(*)[264])(smem0 + 33792);        // 33792 B

    {
        int row = t >> 2, d0 = (t & 3) * 64;
        int s = row & 3, p = row >> 2;
        const float* gx = X + (size_t)(s * 256 + pos0 + p) * 256 + d0;
#pragma unroll
        for (int i = 0; i < 8; ++i) {
            float4 v0 = *(const float4*)(gx + i * 8);
            float4 v1 = *(const float4*)(gx + i * 8 + 4);
            f16x8 o;
            o[0] = (f16)v0.x; o[1] = (f16)v0.y; o[2] = (f16)v0.z; o[3] = (f16)v0.w;
            o[4] = (f16)v1.x; o[5] = (f16)v1.y; o[6] = (f16)v1.z; o[7] = (f16)v1.w;
            *(f16x8*)&Xs[row][d0 + i * 8] = o;
        }
    }
    __syncthreads();

    const f16* mh = MT + (size_t)h * 8 * 256 * 32;
    const int fb = w * 64 + l15;
    f32x4 acc[4][4] = {};
    f16x8 bq[4], bn[4];
#pragma unroll
    for (int nt = 0; nt < 4; ++nt)
        bq[nt] = *(const f16x8*)(mh + (size_t)(fb + nt * 16) * 32 + g * 8);
#pragma unroll
    for (int kk = 0; kk < 8; ++kk) {
        if (kk < 7) {
#pragma unroll
            for (int nt = 0; nt < 4; ++nt)
                bn[nt] = *(const f16x8*)(mh + ((size_t)(kk + 1) * 256 + fb + nt * 16) * 32 + g * 8);
        }
        f16x8 a[4];
#pragma unroll
        for (int rt = 0; rt < 4; ++rt)
            a[rt] = *(const f16x8*)&Xs[rt * 16 + l15][kk * 32 + g * 8];
#pragma unroll
        for (int rt = 0; rt < 4; ++rt)
#pragma unroll
            for (int nt = 0; nt < 4; ++nt)
                acc[rt][nt] = MFMA16(a[rt], bq[nt], acc[rt][nt]);
#pragma unroll
        for (int nt = 0; nt < 4; ++nt) bq[nt] = bn[nt];
    }
#pragma unroll
    for (int rt = 0; rt < 4; ++rt)
#pragma unroll
        for (int nt = 0; nt < 4; ++nt)
#pragma unroll
            for (int j = 0; j < 4; ++j)
                Ts[rt * 16 + g * 4 + j][w * 64 + nt * 16 + l15] = (f16)acc[rt][nt][j];
    __syncthreads();

    f32x4 sacc = {};
#pragma unroll
    for (int ks = 0; ks < 8; ++ks) {
        f16x8 a = *(const f16x8*)&Ts[w * 16 + l15][ks * 32 + g * 8];
        f16x8 b = *(const f16x8*)&Xs[w * 16 + l15][ks * 32 + g * 8];
        sacc = MFMA16(a, b, sacc);
    }
    if ((l15 >> 2) == g) {
        const float scale = 1.0f / 16.0f; // 1/sqrt(256)
        float add = 0.f;
#pragma unroll
        for (int j = 0; j < 4; ++j) {
            float v = sacc[j] * scale;
            float m = v;
            m = fmaxf(m, __shfl_xor(m, 1));
            m = fmaxf(m, __shfl_xor(m, 2));
            float e = expf(v - m);
            float s2 = e;
            s2 += __shfl_xor(s2, 1);
            s2 += __shfl_xor(s2, 2);
            add += e / s2;
        }
        int pg = pos0 + w * 4 + g;
        wpart[((size_t)h * 256 + pg) * 4 + (l15 & 3)] = add;
    }
}

// =====================================================================
// k_small_fin: sum 16 head-partials -> /64 -> softmax(4) -> pool states.
// =====================================================================
__global__ __launch_bounds__(256) void k_small_fin(const float* __restrict__ wpart,
                                                   const float* __restrict__ X,
                                                   float* __restrict__ out_int,
                                                   float* __restrict__ out_w) {
    const int pos = blockIdx.x, t = threadIdx.x;
    __shared__ float red[64];
    __shared__ float ws[4];
    if (t < 64) red[t] = wpart[((size_t)(t >> 2) * 256 + pos) * 4 + (t & 3)];
    __syncthreads();
    if (t == 0) {
        float v[4];
#pragma unroll
        for (int s = 0; s < 4; ++s) {
            float x = 0.f;
            for (int hh = 0; hh < 16; ++hh) x += red[hh * 4 + s];
            v[s] = x * (1.0f / 64.0f);
        }
        float m = fmaxf(fmaxf(v[0], v[1]), fmaxf(v[2], v[3]));
        float sum = 0.f;
#pragma unroll
        for (int s = 0; s < 4; ++s) { v[s] = expf(v[s] - m); sum += v[s]; }
#pragma unroll
        for (int s = 0; s < 4; ++s) ws[s] = v[s] / sum;
    }
    __syncthreads();
    if (t < 4) out_w[pos * 4 + t] = ws[t];
    float v = 0.f;
#pragma unroll
    for (int s = 0; s < 4; ++s) v += ws[s] * X[(size_t)(s * 256 + pos) * 256 + t];
    out_int[(size_t)pos * 256 + t] = v;
}

// =====================================================================
// k_ce_int v5: Tt = M^T X (lane=token), phase2 B-frag == acc layout via
// mfma_f32_16x16x16_f16 -> no Ts LDS, 2 barriers/head. All 16 heads/block.
// Xs: 64x768B swizzled @ [0,49152). part: [4dst][3src][2it][64][4]f32 @ 49152.
// acc_out: [16][1024][2][32]. grid 512, block 256, LDS 73728 -> 2 blk/CU.
// =====================================================================
#define PART_OFF 49152

__global__ __launch_bounds__(256, 2) void k_ce_int(const float* __restrict__ Xg32,
                                                   const f16* __restrict__ MT,
                                                   float* __restrict__ acc_out) {
    const int t = threadIdx.x;
    const int lane = t & 63;
    const int w = t >> 6;       // 0..3
    const int g = lane >> 4;
    const int l15 = lane & 15;
    const int bg = blockIdx.x;

    extern __shared__ __align__(16) char smem[];

    // ---- stage X (64 x 384), f32 -> f16, source-swizzled, linear LDS ----
    {
        const float* xg = Xg32 + (size_t)bg * 64 * 384;
#pragma unroll
        for (int p = 0; p < 12; ++p) {
            int idx = p * 256 + t;
            int row = idx / 48, s = idx - row * 48;
            int c = s ^ (row & 7);
            const float* src = xg + row * 384 + c * 8;
            float4 v0 = *(const float4*)src;
            float4 v1 = *(const float4*)(src + 4);
            f16x8 o;
            o[0] = (f16)v0.x; o[1] = (f16)v0.y; o[2] = (f16)v0.z; o[3] = (f16)v0.w;
            o[4] = (f16)v1.x; o[5] = (f16)v1.y; o[6] = (f16)v1.z; o[7] = (f16)v1.w;
            *(f16x8*)(smem + idx * 16) = o;
        }
    }
    __syncthreads();

    const f16* mall = MT;  // [16][12][384][32], steps linear over (h,kk)
    const int frow = w * 96 + l15;

    f16x8 aq[6], an[6];
#pragma unroll
    for (int ft = 0; ft < 6; ++ft)
        aq[ft] = *(const f16x8*)(mall + ((size_t)0 * 384 + frow + ft * 16) * 32 + g * 8);

    for (int hi = 0; hi < 16; ++hi) {
        // ---- phase 1: Tt = M_h^T @ X; wave owns 96 e'-rows, all 64 tokens ----
        f32x4 acc[6][4] = {};   // [ft][mt]: Tt[96w+16ft+4g+j][16mt+l15]
#pragma unroll
        for (int kk = 0; kk < 12; ++kk) {
            int nstep = hi * 12 + kk + 1;
            if (nstep < 192) {
#pragma unroll
                for (int ft = 0; ft < 6; ++ft)
                    an[ft] = *(const f16x8*)(mall + ((size_t)nstep * 384 + frow + ft * 16) * 32 + g * 8);
            }
            f16x8 xb[4];
#pragma unroll
            for (int mt = 0; mt < 4; ++mt) {
                int row = mt * 16 + l15;
                int ch = kk * 4 + g;
                xb[mt] = *(const f16x8*)(smem + row * 768 + ((ch ^ (row & 7)) << 4));
            }
#pragma unroll
            for (int ft = 0; ft < 6; ++ft)
#pragma unroll
                for (int mt = 0; mt < 4; ++mt)
                    acc[ft][mt] = MFMA16(aq[ft], xb[mt], acc[ft][mt]);
#pragma unroll
            for (int ft = 0; ft < 6; ++ft) aq[ft] = an[ft];
        }

        // ---- convert Tt acc -> f16 B-frags (layout == mfma16 B-frag!) ----
        f16x4 bf[6][4];
#pragma unroll
        for (int ft = 0; ft < 6; ++ft)
#pragma unroll
            for (int mt = 0; mt < 4; ++mt) {
                f32x4 v = acc[ft][mt];
                f16x4 o;
                o[0] = (f16)v[0]; o[1] = (f16)v[1]; o[2] = (f16)v[2]; o[3] = (f16)v[3];
                bf[ft][mt] = o;
            }

        // ---- phase 2: St_w[m,l] partial over wave's 96 e' (no LDS, no bar) ----
        f32x4 s2[2][2][2] = {};  // [b][it][lt]
#pragma unroll
        for (int b = 0; b < 2; ++b)
#pragma unroll
            for (int ks = 0; ks < 6; ++ks)
#pragma unroll
                for (int it = 0; it < 2; ++it) {
                    int r = b * 32 + it * 16 + l15;
                    int ch = 12 * w + 2 * ks + (g >> 1);
                    f16x4 av = *(const f16x4*)(smem + r * 768 + ((ch ^ (r & 7)) << 4) + 8 * (g & 1));
#pragma unroll
                    for (int lt = 0; lt < 2; ++lt)
                        s2[b][it][lt] = MFMA16K16(av, bf[ks][2 * b + lt], s2[b][it][lt]);
                }

        // ---- publish partials (skip own final slice) ----
#pragma unroll
        for (int b = 0; b < 2; ++b)
#pragma unroll
            for (int lt = 0; lt < 2; ++lt) {
                int dst = b * 2 + lt;
                if (dst != w) {
                    int src = w - (w > dst ? 1 : 0);
#pragma unroll
                    for (int it = 0; it < 2; ++it)
                        *(f32x4*)(smem + PART_OFF + (((dst * 3 + src) * 2 + it) << 10) + lane * 16) =
                            s2[b][it][lt];
                }
            }
        __syncthreads();

        // ---- final: wave (b,lt) sums 4 partials, softmax over m, col-sums ----
        {
            const int b = w >> 1, lt = w & 1;
            f32x4 own0, own1;
            if (w == 0)      { own0 = s2[0][0][0]; own1 = s2[0][1][0]; }
            else if (w == 1) { own0 = s2[0][0][1]; own1 = s2[0][1][1]; }
            else if (w == 2) { own0 = s2[1][0][0]; own1 = s2[1][1][0]; }
            else             { own0 = s2[1][0][1]; own1 = s2[1][1][1]; }
            f32x4 ssum[2] = { own0, own1 };
#pragma unroll
            for (int src = 0; src < 3; ++src)
#pragma unroll
                for (int it = 0; it < 2; ++it)
                    ssum[it] += *(const f32x4*)(smem + PART_OFF + (((w * 3 + src) * 2 + it) << 10) + lane * 16);

            const float scale = 0.051031036307982884f; // 1/sqrt(384)
            float mx = -1e30f;
#pragma unroll
            for (int it = 0; it < 2; ++it)
#pragma unroll
                for (int j = 0; j < 4; ++j) mx = fmaxf(mx, ssum[it][j] * scale);
            mx = fmaxf(mx, __shfl_xor(mx, 16));
            mx = fmaxf(mx, __shfl_xor(mx, 32));
            float e[2][4];
            float den = 0.f;
#pragma unroll
            for (int it = 0; it < 2; ++it)
#pragma unroll
                for (int j = 0; j < 4; ++j) {
                    e[it][j] = expf(ssum[it][j] * scale - mx);
                    den += e[it][j];
                }
            den += __shfl_xor(den, 16);
            den += __shfl_xor(den, 32);
            float inv = 1.f / den;
            float cs[2][4];
#pragma unroll
            for (int it = 0; it < 2; ++it)
#pragma unroll
                for (int j = 0; j < 4; ++j) {
                    float v = e[it][j] * inv;
                    v += __shfl_xor(v, 1);
                    v += __shfl_xor(v, 2);
                    v += __shfl_xor(v, 4);
                    v += __shfl_xor(v, 8);
                    cs[it][j] = v;
                }
            if (l15 == 0) {
                float* o = acc_out + (((size_t)hi * 1024 + bg * 2 + b) * 2 + lt) * 32;
#pragma unroll
                for (int it = 0; it < 2; ++it)
#pragma unroll
                    for (int j = 0; j < 4; ++j)
                        o[it * 16 + g * 4 + j] = cs[it][j];
            }
        }
        __syncthreads();  // protect part for next head
    }
}

// =====================================================================
// k_ce_pool: w = softmax(sum_{h,lt} accp / 512); pooled = sum_m w[m]*exv
// accp: [16][1024][2][32]
// =====================================================================
__global__ __launch_bounds__(128) void k_ce_pool(const float* __restrict__ accp,
                                                 const float* __restrict__ exv,
                                                 float* __restrict__ pooled) {
    const int b = blockIdx.x;
    const int t = threadIdx.x;
    __shared__ float wm[32];
    __shared__ float ww[32];
    if (t < 32) {
        float s = 0.f;
#pragma unroll
        for (int h = 0; h < 16; ++h) {
            s += accp[(((size_t)h * 1024 + b) * 2 + 0) * 32 + t];
            s += accp[(((size_t)h * 1024 + b) * 2 + 1) * 32 + t];
        }
        wm[t] = s * (1.0f / 512.0f);
    }
    __syncthreads();
    if (t == 0) {
        float m = wm[0];
        for (int i = 1; i < 32; ++i) m = fmaxf(m, wm[i]);
        float s = 0.f;
        for (int i = 0; i < 32; ++i) { float e = expf(wm[i] - m); ww[i] = e; s += e; }
        float inv = 1.f / s;
        for (int i = 0; i < 32; ++i) ww[i] *= inv;
    }
    __syncthreads();
    for (int d = t; d < 384; d += 128) {
        float v = 0.f;
#pragma unroll
        for (int m = 0; m < 32; ++m) v += ww[m] * exv[((size_t)b * 32 + m) * 384 + d];
        pooled[(size_t)b * 384 + d] = v;
    }
}

// =====================================================================
extern "C" void kernel_launch(void* const* d_in, const int* in_sizes, int n_in,
                              void* d_out, int out_size, void* d_ws, size_t ws_size,
                              hipStream_t stream) {
    const float* h_V    = (const float*)d_in[0];
    const float* h_EXV  = (const float*)d_in[1];
    const float* W_hV   = (const float*)d_in[2];
    const float* b_hV   = (const float*)d_in[3];
    const float* Wq_hv  = (const float*)d_in[4];
    const float* Wk_hv  = (const float*)d_in[5];
    const float* Wq_ce  = (const float*)d_in[6];
    const float* Wk_ce  = (const float*)d_in[7];
    const float* W_ce   = (const float*)d_in[8];
    const float* b_ce   = (const float*)d_in[9];
    const float* Wq_sce = (const float*)d_in[10];
    const float* Wk_sce = (const float*)d_in[11];
    float* out = (float*)d_out;

    char* ws = (char*)d_ws;
    f16*   mt_hv  = (f16*)(ws + 0);           //  2,097,152
    f16*   mt_sce = (f16*)(ws + 2097152);     //  2,097,152
    f16*   mt_ce  = (f16*)(ws + 4194304);     //  4,718,592
    float* hv     = (float*)(ws + 8912896);   //  1,048,576
    float* ce     = (float*)(ws + 9961472);   //  1,048,576
    float* accp   = (float*)(ws + 11010048);  //  4,194,304
    float* pooled = (float*)(ws + 15204352);  //  1,572,864  (total ~16.8 MB)
    float* wpart  = accp;                     // alias: lifetimes ordered

    k_mt<<<dim3(16, 16), 256, 0, stream>>>(Wq_hv, Wk_hv, mt_hv, 256);
    k_mt<<<dim3(16, 36), 256, 0, stream>>>(Wq_ce, Wk_ce, mt_ce, 384);
    k_mt<<<dim3(16, 16), 256, 0, stream>>>(Wq_sce, Wk_sce, mt_sce, 256);
    k_lin<<<256, 256, 0, stream>>>(h_V, W_hV, b_hV, hv, 128);
    k_small_int<<<dim3(16, 16), 256, 67584, stream>>>(hv, mt_hv, wpart);
    k_small_fin<<<256, 256, 0, stream>>>(wpart, hv, out + 0, out + 65536);
    k_ce_int<<<dim3(512), 256, 73728, stream>>>(h_EXV, mt_ce, accp);
    k_ce_pool<<<1024, 128, 0, stream>>>(accp, h_EXV, pooled);
    k_lin<<<256, 256, 0, stream>>>(pooled, W_ce, b_ce, ce, 384);
    k_small_int<<<dim3(16, 16), 256, 67584, stream>>>(ce, mt_sce, wpart);
    k_small_fin<<<256, 256, 0, stream>>>(wpart, ce, out + 66560, out + 132096);
}

// Round 6
// 315.348 us; speedup vs baseline: 3.2633x; 1.0430x over previous
//
#include <hip/hip_runtime.h>

typedef _Float16 f16;
typedef _Float16 f16x8 __attribute__((ext_vector_type(8)));
typedef _Float16 f16x4 __attribute__((ext_vector_type(4)));
typedef float f32x4 __attribute__((ext_vector_type(4)));

#define MFMA16(a, b, c) __builtin_amdgcn_mfma_f32_16x16x32_f16(a, b, c, 0, 0, 0)
#define MFMA16K16(a, b, c) __builtin_amdgcn_mfma_f32_16x16x16f16(a, b, c, 0, 0, 0)

// =====================================================================
// k_mt: M_h = Wq_h^T Wk_h, stored K-blocked:
//   MT[((h*nkk + (e>>5))*H + f)*32 + (e&31)] = sum_d Wq[h*H+d][e]*Wk[h*H+d][f]
// =====================================================================
__global__ __launch_bounds__(256) void k_mt(const float* __restrict__ Wq,
                                            const float* __restrict__ Wk,
                                            f16* __restrict__ MT, int H) {
    const int h = blockIdx.x;
    const int ntile = H >> 6;
    const int nkk = H >> 5;
    const int frow = (blockIdx.y / ntile) * 64;
    const int ecol = (blockIdx.y % ntile) * 64;
    const int t = threadIdx.x;
    const int lane = t & 63;
    const int w = t >> 6;
    const int wr = w >> 1, wc = w & 1;

    __shared__ __align__(16) f16 As[64][40];
    __shared__ __align__(16) f16 Ks[64][40];

    f32x4 acc[2][2] = {};
    const int d = t >> 3;
    const int e8 = (t & 7) * 8;

    for (int kk = 0; kk < nkk; ++kk) {
        const float* gq = Wq + (size_t)(h * H + kk * 32 + d) * H + ecol + e8;
        const float* gk = Wk + (size_t)(h * H + kk * 32 + d) * H + frow + e8;
        float q[8], k[8];
#pragma unroll
        for (int i = 0; i < 8; ++i) { q[i] = gq[i]; k[i] = gk[i]; }
        __syncthreads();
#pragma unroll
        for (int i = 0; i < 8; ++i) { As[e8 + i][d] = (f16)q[i]; Ks[e8 + i][d] = (f16)k[i]; }
        __syncthreads();
        f16x8 a[2], b[2];
#pragma unroll
        for (int rt = 0; rt < 2; ++rt)
            a[rt] = *(const f16x8*)&Ks[wr * 32 + rt * 16 + (lane & 15)][(lane >> 4) * 8];
#pragma unroll
        for (int nt = 0; nt < 2; ++nt)
            b[nt] = *(const f16x8*)&As[wc * 32 + nt * 16 + (lane & 15)][(lane >> 4) * 8];
#pragma unroll
        for (int rt = 0; rt < 2; ++rt)
#pragma unroll
            for (int nt = 0; nt < 2; ++nt)
                acc[rt][nt] = MFMA16(a[rt], b[nt], acc[rt][nt]);
    }
#pragma unroll
    for (int rt = 0; rt < 2; ++rt)
#pragma unroll
        for (int nt = 0; nt < 2; ++nt)
#pragma unroll
            for (int j = 0; j < 4; ++j) {
                int f = frow + wr * 32 + rt * 16 + (lane >> 4) * 4 + j;
                int e = ecol + wc * 32 + nt * 16 + (lane & 15);
                MT[(((size_t)h * nkk + (e >> 5)) * H + f) * 32 + (e & 31)] = (f16)acc[rt][nt][j];
            }
}

// =====================================================================
// k_lin: out[r][j] = sum_d in[r][d]*W[j][d] + b[j], J=256, 4 rows/block.
// =====================================================================
__global__ __launch_bounds__(256) void k_lin(const float* __restrict__ in,
                                             const float* __restrict__ W,
                                             const float* __restrict__ bias,
                                             float* __restrict__ out, int K) {
    const int t = threadIdx.x;
    const int r0 = blockIdx.x * 4;
    __shared__ float ins[4][384];
    __shared__ float Ws[256][33];
#pragma unroll
    for (int r = 0; r < 4; ++r)
        for (int off = t; off < K; off += 256)
            ins[r][off] = in[(size_t)(r0 + r) * K + off];
    float acc[4] = {};
    for (int d0 = 0; d0 < K; d0 += 32) {
        __syncthreads();
        for (int i = t; i < 256 * 32; i += 256) {
            int j = i >> 5, dd = i & 31;
            Ws[j][dd] = W[(size_t)j * K + d0 + dd];
        }
        __syncthreads();
#pragma unroll 8
        for (int dd = 0; dd < 32; ++dd) {
            float wv = Ws[t][dd];
#pragma unroll
            for (int r = 0; r < 4; ++r) acc[r] += wv * ins[r][d0 + dd];
        }
    }
    float bv = bias[t];
#pragma unroll
    for (int r = 0; r < 4; ++r) out[(size_t)(r0 + r) * 256 + t] = acc[r] + bv;
}

// =====================================================================
// k_small_int v4: 4 pos-groups/block (16 X-rows) -> 1024 blocks, 4 blk/CU.
// Phase 2 duplicated across waves (cheap: 8 MFMA), wave0 writes.
// grid (64, 16), block 256, static LDS ~17 KB.
// =====================================================================
__global__ __launch_bounds__(256) void k_small_int(const float* __restrict__ X,
                                                   const f16* __restrict__ MT,
                                                   float* __restrict__ wpart) {
    const int t = threadIdx.x;
    const int lane = t & 63;
    const int w = t >> 6;
    const int g = lane >> 4;
    const int l15 = lane & 15;
    const int pos0 = blockIdx.x * 4;
    const int h = blockIdx.y;

    __shared__ __align__(16) f16 Xs[16][264];
    __shared__ __align__(16) f16 Ts[16][264];

    {
        int row = t >> 4, d0 = (t & 15) * 16;
        int s = row & 3, p = row >> 2;
        const float* gx = X + (size_t)(s * 256 + pos0 + p) * 256 + d0;
#pragma unroll
        for (int i = 0; i < 16; i += 8) {
            float4 v0 = *(const float4*)(gx + i);
            float4 v1 = *(const float4*)(gx + i + 4);
            f16x8 o;
            o[0] = (f16)v0.x; o[1] = (f16)v0.y; o[2] = (f16)v0.z; o[3] = (f16)v0.w;
            o[4] = (f16)v1.x; o[5] = (f16)v1.y; o[6] = (f16)v1.z; o[7] = (f16)v1.w;
            *(f16x8*)&Xs[row][d0 + i] = o;
        }
    }
    __syncthreads();

    // phase 1: T = X(16x256) @ M_h; wave w owns cols w*64+[0,64)
    const f16* mh = MT + (size_t)h * 8 * 256 * 32;
    const int fb = w * 64 + l15;
    f32x4 acc[4] = {};
    f16x8 bq[4], bn[4];
#pragma unroll
    for (int nt = 0; nt < 4; ++nt)
        bq[nt] = *(const f16x8*)(mh + (size_t)(fb + nt * 16) * 32 + g * 8);
#pragma unroll
    for (int kk = 0; kk < 8; ++kk) {
        if (kk < 7) {
#pragma unroll
            for (int nt = 0; nt < 4; ++nt)
                bn[nt] = *(const f16x8*)(mh + ((size_t)(kk + 1) * 256 + fb + nt * 16) * 32 + g * 8);
        }
        f16x8 a = *(const f16x8*)&Xs[l15][kk * 32 + g * 8];
#pragma unroll
        for (int nt = 0; nt < 4; ++nt) acc[nt] = MFMA16(a, bq[nt], acc[nt]);
#pragma unroll
        for (int nt = 0; nt < 4; ++nt) bq[nt] = bn[nt];
    }
#pragma unroll
    for (int nt = 0; nt < 4; ++nt)
#pragma unroll
        for (int j = 0; j < 4; ++j)
            Ts[g * 4 + j][w * 64 + nt * 16 + l15] = (f16)acc[nt][j];
    __syncthreads();

    // phase 2 (duplicated across waves; no further barrier)
    f32x4 sacc = {};
#pragma unroll
    for (int ks = 0; ks < 8; ++ks) {
        f16x8 a = *(const f16x8*)&Ts[l15][ks * 32 + g * 8];
        f16x8 b = *(const f16x8*)&Xs[l15][ks * 32 + g * 8];
        sacc = MFMA16(a, b, sacc);
    }
    if (w == 0 && (l15 >> 2) == g) {
        const float scale = 1.0f / 16.0f; // 1/sqrt(256)
        float add = 0.f;
#pragma unroll
        for (int j = 0; j < 4; ++j) {
            float v = sacc[j] * scale;
            float m = v;
            m = fmaxf(m, __shfl_xor(m, 1));
            m = fmaxf(m, __shfl_xor(m, 2));
            float e = expf(v - m);
            float s2 = e;
            s2 += __shfl_xor(s2, 1);
            s2 += __shfl_xor(s2, 2);
            add += e / s2;
        }
        int pg = pos0 + g;
        wpart[((size_t)h * 256 + pg) * 4 + (l15 & 3)] = add;
    }
}

// =====================================================================
// k_small_fin: sum 16 head-partials -> /64 -> softmax(4) -> pool states.
// =====================================================================
__global__ __launch_bounds__(256) void k_small_fin(const float* __restrict__ wpart,
                                                   const float* __restrict__ X,
                                                   float* __restrict__ out_int,
                                                   float* __restrict__ out_w) {
    const int pos = blockIdx.x, t = threadIdx.x;
    __shared__ float red[64];
    __shared__ float ws[4];
    if (t < 64) red[t] = wpart[((size_t)(t >> 2) * 256 + pos) * 4 + (t & 3)];
    __syncthreads();
    if (t == 0) {
        float v[4];
#pragma unroll
        for (int s = 0; s < 4; ++s) {
            float x = 0.f;
            for (int hh = 0; hh < 16; ++hh) x += red[hh * 4 + s];
            v[s] = x * (1.0f / 64.0f);
        }
        float m = fmaxf(fmaxf(v[0], v[1]), fmaxf(v[2], v[3]));
        float sum = 0.f;
#pragma unroll
        for (int s = 0; s < 4; ++s) { v[s] = expf(v[s] - m); sum += v[s]; }
#pragma unroll
        for (int s = 0; s < 4; ++s) ws[s] = v[s] / sum;
    }
    __syncthreads();
    if (t < 4) out_w[pos * 4 + t] = ws[t];
    float v = 0.f;
#pragma unroll
    for (int s = 0; s < 4; ++s) v += ws[s] * X[(size_t)(s * 256 + pos) * 256 + t];
    out_int[(size_t)pos * 256 + t] = v;
}

// =====================================================================
// k_ce_int v6: depth-2 M prefetch (3 reg buffers, static idx), setprio
// around MFMA clusters. Tt = M^T X; phase2 B-frag == acc layout (K16).
// Xs: 64x768B swizzled @ [0,49152). part @ 49152 (24576 B).
// acc_out: [16][1024][2][32]. grid 512, block 256, LDS 73728 -> 2 blk/CU.
// =====================================================================
#define PART_OFF 49152

__global__ __launch_bounds__(256, 2) void k_ce_int(const float* __restrict__ Xg32,
                                                   const f16* __restrict__ MT,
                                                   float* __restrict__ acc_out) {
    const int t = threadIdx.x;
    const int lane = t & 63;
    const int w = t >> 6;       // 0..3
    const int g = lane >> 4;
    const int l15 = lane & 15;
    const int bg = blockIdx.x;

    extern __shared__ __align__(16) char smem[];

    // ---- stage X (64 x 384), f32 -> f16, source-swizzled, linear LDS ----
    {
        const float* xg = Xg32 + (size_t)bg * 64 * 384;
#pragma unroll
        for (int p = 0; p < 12; ++p) {
            int idx = p * 256 + t;
            int row = idx / 48, s = idx - row * 48;
            int c = s ^ (row & 7);
            const float* src = xg + row * 384 + c * 8;
            float4 v0 = *(const float4*)src;
            float4 v1 = *(const float4*)(src + 4);
            f16x8 o;
            o[0] = (f16)v0.x; o[1] = (f16)v0.y; o[2] = (f16)v0.z; o[3] = (f16)v0.w;
            o[4] = (f16)v1.x; o[5] = (f16)v1.y; o[6] = (f16)v1.z; o[7] = (f16)v1.w;
            *(f16x8*)(smem + idx * 16) = o;
        }
    }
    __syncthreads();

    const f16* mall = MT;  // [16][12][384][32], steps linear over (h,kk)
    const int frow = w * 96 + l15;

    // depth-2 prefetch: 3 buffers, A[step%3]
    f16x8 A[3][6];
#pragma unroll
    for (int ft = 0; ft < 6; ++ft) {
        A[0][ft] = *(const f16x8*)(mall + ((size_t)0 * 384 + frow + ft * 16) * 32 + g * 8);
        A[1][ft] = *(const f16x8*)(mall + ((size_t)1 * 384 + frow + ft * 16) * 32 + g * 8);
    }

    for (int hi = 0; hi < 16; ++hi) {
        // ---- phase 1: Tt = M_h^T @ X; wave owns 96 e'-rows, all 64 tokens ----
        f32x4 acc[6][4] = {};   // [ft][mt]: Tt[96w+16ft+4g+j][16mt+l15]
#pragma unroll
        for (int kk = 0; kk < 12; ++kk) {
            {   // issue loads for step kk+2 into buffer (kk+2)%3
                int step = hi * 12 + kk + 2;
                int ns = step < 192 ? step : 191;   // clamped tail (harmless)
#pragma unroll
                for (int ft = 0; ft < 6; ++ft)
                    A[(kk + 2) % 3][ft] =
                        *(const f16x8*)(mall + ((size_t)ns * 384 + frow + ft * 16) * 32 + g * 8);
            }
            f16x8 xb[4];
#pragma unroll
            for (int mt = 0; mt < 4; ++mt) {
                int row = mt * 16 + l15;
                int ch = kk * 4 + g;
                xb[mt] = *(const f16x8*)(smem + row * 768 + ((ch ^ (row & 7)) << 4));
            }
            __builtin_amdgcn_s_setprio(1);
#pragma unroll
            for (int ft = 0; ft < 6; ++ft)
#pragma unroll
                for (int mt = 0; mt < 4; ++mt)
                    acc[ft][mt] = MFMA16(A[kk % 3][ft], xb[mt], acc[ft][mt]);
            __builtin_amdgcn_s_setprio(0);
        }

        // ---- convert Tt acc -> f16 B-frags (layout == mfma16 B-frag) ----
        f16x4 bf[6][4];
#pragma unroll
        for (int ft = 0; ft < 6; ++ft)
#pragma unroll
            for (int mt = 0; mt < 4; ++mt) {
                f32x4 v = acc[ft][mt];
                f16x4 o;
                o[0] = (f16)v[0]; o[1] = (f16)v[1]; o[2] = (f16)v[2]; o[3] = (f16)v[3];
                bf[ft][mt] = o;
            }

        // ---- phase 2: St_w[m,l] partial over wave's 96 e' (no LDS, no bar) ----
        f32x4 s2[2][2][2] = {};  // [b][it][lt]
#pragma unroll
        for (int b = 0; b < 2; ++b)
#pragma unroll
            for (int ks = 0; ks < 6; ++ks)
#pragma unroll
                for (int it = 0; it < 2; ++it) {
                    int r = b * 32 + it * 16 + l15;
                    int ch = 12 * w + 2 * ks + (g >> 1);
                    f16x4 av = *(const f16x4*)(smem + r * 768 + ((ch ^ (r & 7)) << 4) + 8 * (g & 1));
#pragma unroll
                    for (int lt = 0; lt < 2; ++lt)
                        s2[b][it][lt] = MFMA16K16(av, bf[ks][2 * b + lt], s2[b][it][lt]);
                }

        // ---- publish partials (skip own final slice) ----
#pragma unroll
        for (int b = 0; b < 2; ++b)
#pragma unroll
            for (int lt = 0; lt < 2; ++lt) {
                int dst = b * 2 + lt;
                if (dst != w) {
                    int src = w - (w > dst ? 1 : 0);
#pragma unroll
                    for (int it = 0; it < 2; ++it)
                        *(f32x4*)(smem + PART_OFF + (((dst * 3 + src) * 2 + it) << 10) + lane * 16) =
                            s2[b][it][lt];
                }
            }
        __syncthreads();

        // ---- final: wave (b,lt) sums 4 partials, softmax over m, col-sums ----
        {
            const int b = w >> 1, lt = w & 1;
            f32x4 own0, own1;
            if (w == 0)      { own0 = s2[0][0][0]; own1 = s2[0][1][0]; }
            else if (w == 1) { own0 = s2[0][0][1]; own1 = s2[0][1][1]; }
            else if (w == 2) { own0 = s2[1][0][0]; own1 = s2[1][1][0]; }
            else             { own0 = s2[1][0][1]; own1 = s2[1][1][1]; }
            f32x4 ssum[2] = { own0, own1 };
#pragma unroll
            for (int src = 0; src < 3; ++src)
#pragma unroll
                for (int it = 0; it < 2; ++it)
                    ssum[it] += *(const f32x4*)(smem + PART_OFF + (((w * 3 + src) * 2 + it) << 10) + lane * 16);

            const float scale = 0.051031036307982884f; // 1/sqrt(384)
            float mx = -1e30f;
#pragma unroll
            for (int it = 0; it < 2; ++it)
#pragma unroll
                for (int j = 0; j < 4; ++j) mx = fmaxf(mx, ssum[it][j] * scale);
            mx = fmaxf(mx, __shfl_xor(mx, 16));
            mx = fmaxf(mx, __shfl_xor(mx, 32));
            float e[2][4];
            float den = 0.f;
#pragma unroll
            for (int it = 0; it < 2; ++it)
#pragma unroll
                for (int j = 0; j < 4; ++j) {
                    e[it][j] = expf(ssum[it][j] * scale - mx);
                    den += e[it][j];
                }
            den += __shfl_xor(den, 16);
            den += __shfl_xor(den, 32);
            float inv = 1.f / den;
            float cs[2][4];
#pragma unroll
            for (int it = 0; it < 2; ++it)
#pragma unroll
                for (int j = 0; j < 4; ++j) {
                    float v = e[it][j] * inv;
                    v += __shfl_xor(v, 1);
                    v += __shfl_xor(v, 2);
                    v += __shfl_xor(v, 4);
                    v += __shfl_xor(v, 8);
                    cs[it][j] = v;
                }
            if (l15 == 0) {
                float* o = acc_out + (((size_t)hi * 1024 + bg * 2 + b) * 2 + lt) * 32;
#pragma unroll
                for (int it = 0; it < 2; ++it)
#pragma unroll
                    for (int j = 0; j < 4; ++j)
                        o[it * 16 + g * 4 + j] = cs[it][j];
            }
        }
        __syncthreads();  // protect part for next head
    }
}

// =====================================================================
// k_ce_pool: w = softmax(sum_{h,lt} accp / 512); pooled = sum_m w[m]*exv
// accp: [16][1024][2][32]
// =====================================================================
__global__ __launch_bounds__(128) void k_ce_pool(const float* __restrict__ accp,
                                                 const float* __restrict__ exv,
                                                 float* __restrict__ pooled) {
    const int b = blockIdx.x;
    const int t = threadIdx.x;
    __shared__ float wm[32];
    __shared__ float ww[32];
    if (t < 32) {
        float s = 0.f;
#pragma unroll
        for (int h = 0; h < 16; ++h) {
            s += accp[(((size_t)h * 1024 + b) * 2 + 0) * 32 + t];
            s += accp[(((size_t)h * 1024 + b) * 2 + 1) * 32 + t];
        }
        wm[t] = s * (1.0f / 512.0f);
    }
    __syncthreads();
    if (t == 0) {
        float m = wm[0];
        for (int i = 1; i < 32; ++i) m = fmaxf(m, wm[i]);
        float s = 0.f;
        for (int i = 0; i < 32; ++i) { float e = expf(wm[i] - m); ww[i] = e; s += e; }
        float inv = 1.f / s;
        for (int i = 0; i < 32; ++i) ww[i] *= inv;
    }
    __syncthreads();
    for (int d = t; d < 384; d += 128) {
        float v = 0.f;
#pragma unroll
        for (int m = 0; m < 32; ++m) v += ww[m] * exv[((size_t)b * 32 + m) * 384 + d];
        pooled[(size_t)b * 384 + d] = v;
    }
}

// =====================================================================
extern "C" void kernel_launch(void* const* d_in, const int* in_sizes, int n_in,
                              void* d_out, int out_size, void* d_ws, size_t ws_size,
                              hipStream_t stream) {
    const float* h_V    = (const float*)d_in[0];
    const float* h_EXV  = (const float*)d_in[1];
    const float* W_hV   = (const float*)d_in[2];
    const float* b_hV   = (const float*)d_in[3];
    const float* Wq_hv  = (const float*)d_in[4];
    const float* Wk_hv  = (const float*)d_in[5];
    const float* Wq_ce  = (const float*)d_in[6];
    const float* Wk_ce  = (const float*)d_in[7];
    const float* W_ce   = (const float*)d_in[8];
    const float* b_ce   = (const float*)d_in[9];
    const float* Wq_sce = (const float*)d_in[10];
    const float* Wk_sce = (const float*)d_in[11];
    float* out = (float*)d_out;

    char* ws = (char*)d_ws;
    f16*   mt_hv  = (f16*)(ws + 0);           //  2,097,152
    f16*   mt_sce = (f16*)(ws + 2097152);     //  2,097,152
    f16*   mt_ce  = (f16*)(ws + 4194304);     //  4,718,592
    float* hv     = (float*)(ws + 8912896);   //  1,048,576
    float* ce     = (float*)(ws + 9961472);   //  1,048,576
    float* accp   = (float*)(ws + 11010048);  //  4,194,304
    float* pooled = (float*)(ws + 15204352);  //  1,572,864  (total ~16.8 MB)
    float* wpart  = accp;                     // alias: lifetimes ordered

    k_mt<<<dim3(16, 16), 256, 0, stream>>>(Wq_hv, Wk_hv, mt_hv, 256);
    k_mt<<<dim3(16, 36), 256, 0, stream>>>(Wq_ce, Wk_ce, mt_ce, 384);
    k_mt<<<dim3(16, 16), 256, 0, stream>>>(Wq_sce, Wk_sce, mt_sce, 256);
    k_lin<<<256, 256, 0, stream>>>(h_V, W_hV, b_hV, hv, 128);
    k_small_int<<<dim3(64, 16), 256, 0, stream>>>(hv, mt_hv, wpart);
    k_small_fin<<<256, 256, 0, stream>>>(wpart, hv, out + 0, out + 65536);
    k_ce_int<<<dim3(512), 256, 73728, stream>>>(h_EXV, mt_ce, accp);
    k_ce_pool<<<1024, 128, 0, stream>>>(accp, h_EXV, pooled);
    k_lin<<<256, 256, 0, stream>>>(pooled, W_ce, b_ce, ce, 384);
    k_small_int<<<dim3(64, 16), 256, 0, stream>>>(ce, mt_sce, wpart);
    k_small_fin<<<256, 256, 0, stream>>>(wpart, ce, out + 66560, out + 132096);
}